// Round 5
// baseline (1344.047 us; speedup 1.0000x reference)
//
#include <hip/hip_runtime.h>

#define SS   2048
#define DD   2560
#define HH   32
#define DHH  80
#define DPAD 96
#define NII  10240
#define NTOK 4096

typedef __attribute__((ext_vector_type(8))) __bf16 bf16x8;
typedef __attribute__((ext_vector_type(4))) float  f32x4;

__device__ __forceinline__ float bf2f(unsigned short h) {
  union { unsigned u; float f; } c; c.u = ((unsigned)h) << 16; return c.f;
}
__device__ __forceinline__ unsigned short f2bf(float f) {
  union { float f; unsigned u; } c; c.f = f;
  unsigned r = c.u + 0x7FFFu + ((c.u >> 16) & 1u);
  return (unsigned short)(r >> 16);
}

__device__ __forceinline__ void gl_lds16(const void* gptr, void* lptr) {
  __builtin_amdgcn_global_load_lds((__attribute__((address_space(1))) void*)gptr,
                                   (__attribute__((address_space(3))) void*)lptr,
                                   16, 0, 0);
}

// ---------------- weight transpose: W[K][N] fp32 -> Wt[N][K] bf16 ----------------
__global__ __launch_bounds__(256) void wt_transpose(const float* __restrict__ W,
                                                    unsigned short* __restrict__ Wt,
                                                    int K, int N) {
  __shared__ float tile[32][33];
  const int tx = threadIdx.x & 31, ty = threadIdx.x >> 5;
  const int n0 = blockIdx.x * 32, k0 = blockIdx.y * 32;
#pragma unroll
  for (int i = 0; i < 32; i += 8)
    tile[ty + i][tx] = W[(size_t)(k0 + ty + i) * N + n0 + tx];
  __syncthreads();
#pragma unroll
  for (int i = 0; i < 32; i += 8)
    Wt[(size_t)(n0 + ty + i) * K + k0 + tx] = f2bf(tile[tx][ty + i]);
}

// ---------------- LayerNorm: fp32 in -> bf16 out ----------------
__global__ __launch_bounds__(256) void ln_kernel(const float* __restrict__ X,
                                                 const float* __restrict__ G,
                                                 const float* __restrict__ Bb,
                                                 unsigned short* __restrict__ Xo) {
  const int row = blockIdx.x;
  const float4* xr = (const float4*)(X + (size_t)row * DD);
  float s = 0.f, ss = 0.f;
  for (int i = threadIdx.x; i < DD / 4; i += 256) {
    float4 v = xr[i];
    s  += v.x + v.y + v.z + v.w;
    ss += v.x * v.x + v.y * v.y + v.z * v.z + v.w * v.w;
  }
#pragma unroll
  for (int o = 32; o > 0; o >>= 1) { s += __shfl_down(s, o, 64); ss += __shfl_down(ss, o, 64); }
  __shared__ float red[8];
  const int w = threadIdx.x >> 6;
  if ((threadIdx.x & 63) == 0) { red[w] = s; red[4 + w] = ss; }
  __syncthreads();
  if (threadIdx.x == 0) {
    float ts  = red[0] + red[1] + red[2] + red[3];
    float tss = red[4] + red[5] + red[6] + red[7];
    float mu  = ts * (1.f / DD);
    float var = tss * (1.f / DD) - mu * mu;
    red[0] = mu; red[1] = rsqrtf(var + 1e-5f);
  }
  __syncthreads();
  const float mu = red[0], rstd = red[1];
  const float4* gr = (const float4*)G;
  const float4* br = (const float4*)Bb;
  for (int i = threadIdx.x; i < DD / 4; i += 256) {
    float4 v = xr[i], g = gr[i], b = br[i];
    ushort4 o;
    o.x = f2bf((v.x - mu) * rstd * g.x + b.x);
    o.y = f2bf((v.y - mu) * rstd * g.y + b.y);
    o.z = f2bf((v.z - mu) * rstd * g.z + b.z);
    o.w = f2bf((v.w - mu) * rstd * g.w + b.w);
    *(ushort4*)&Xo[(size_t)row * DD + i * 4] = o;
  }
}

// ---------------- RoPE + head-layout ----------------
__global__ __launch_bounds__(256) void rope_kernel(const unsigned short* __restrict__ qkv,
                                                   unsigned short* __restrict__ Qp,
                                                   unsigned short* __restrict__ Kp,
                                                   unsigned short* __restrict__ Vt) {
  const int tok = blockIdx.x;
  const int b = tok / SS, s = tok % SS;
  __shared__ float cs[16], sn[16];
  if (threadIdx.x < 16) {
    float inv = powf(10000.f, -(float)threadIdx.x / 16.f);
    float ang = (float)s * inv;
    cs[threadIdx.x] = cosf(ang);
    sn[threadIdx.x] = sinf(ang);
  }
  __syncthreads();
  const unsigned short* row = qkv + (size_t)tok * (3 * DD);
  for (int idx = threadIdx.x; idx < 2 * HH * DPAD; idx += 256) {
    const int which = idx / (HH * DPAD);
    const int rrem  = idx % (HH * DPAD);
    const int h = rrem / DPAD, d = rrem % DPAD;
    float val = 0.f;
    if (d < DHH) {
      const unsigned short* base = row + which * DD + h * DHH;
      if (d < 16) {
        float x1 = bf2f(base[d]), x2 = bf2f(base[d + 16]);
        val = x1 * cs[d] - x2 * sn[d];
      } else if (d < 32) {
        int i2 = d - 16;
        float x1 = bf2f(base[i2]), x2 = bf2f(base[d]);
        val = x2 * cs[i2] + x1 * sn[i2];
      } else {
        val = bf2f(base[d]);
      }
    }
    unsigned short* outp = which ? Kp : Qp;
    outp[(((size_t)b * HH + h) * SS + s) * DPAD + d] = f2bf(val);
  }
  for (int idx = threadIdx.x; idx < DD; idx += 256) {
    const int h = idx / DHH, d = idx % DHH;
    Vt[(((size_t)b * HH + h) * DHH + d) * SS + s] = row[2 * DD + idx];
  }
}

// ---------------- flash attention (causal), 2-wave blocks, 16 q-rows/wave, KVBLK=64 ----------------
__global__ __launch_bounds__(128) void attn_kernel(const unsigned short* __restrict__ Qp,
                                                   const unsigned short* __restrict__ Kp,
                                                   const unsigned short* __restrict__ Vt,
                                                   unsigned short* __restrict__ O) {
  const int bid = blockIdx.x;
  const int bh = bid & 63;
  const int p = 63 - (bid >> 6);        // heavy first
  const int w = threadIdx.x >> 6;
  const int tile = p * 2 + w;
  const int lane = threadIdx.x & 63;
  const int lr = lane & 15, lg = lane >> 4;
  const int q0 = tile * 16;
  const unsigned short* Qh = Qp + (size_t)bh * SS * DPAD;
  const unsigned short* Kh = Kp + (size_t)bh * SS * DPAD;
  const unsigned short* Vh = Vt + (size_t)bh * DHH * SS;
  __shared__ __align__(16) char Plds[2][2048];
  char* Pb = Plds[w];

  bf16x8 qf[3];
#pragma unroll
  for (int c = 0; c < 3; ++c)
    qf[c] = *(const bf16x8*)&Qh[(size_t)(q0 + lr) * DPAD + c * 32 + lg * 8];

  f32x4 oacc[5];
#pragma unroll
  for (int d = 0; d < 5; ++d) oacc[d] = (f32x4){0.f, 0.f, 0.f, 0.f};
  float mrow[4], lrow[4];
#pragma unroll
  for (int r = 0; r < 4; ++r) { mrow[r] = -1e30f; lrow[r] = 0.f; }

  const float scl = 0.11180339887498949f;
  const int nt = q0 / 64 + 1;
  for (int t = 0; t < nt; ++t) {
    const int kv0 = t * 64;
    f32x4 s0 = (f32x4){0.f, 0.f, 0.f, 0.f};
    f32x4 s1 = (f32x4){0.f, 0.f, 0.f, 0.f};
    f32x4 s2 = (f32x4){0.f, 0.f, 0.f, 0.f};
    f32x4 s3 = (f32x4){0.f, 0.f, 0.f, 0.f};
#pragma unroll
    for (int c = 0; c < 3; ++c) {
      bf16x8 k0 = *(const bf16x8*)&Kh[(size_t)(kv0 +      lr) * DPAD + c * 32 + lg * 8];
      bf16x8 k1 = *(const bf16x8*)&Kh[(size_t)(kv0 + 16 + lr) * DPAD + c * 32 + lg * 8];
      bf16x8 k2 = *(const bf16x8*)&Kh[(size_t)(kv0 + 32 + lr) * DPAD + c * 32 + lg * 8];
      bf16x8 k3 = *(const bf16x8*)&Kh[(size_t)(kv0 + 48 + lr) * DPAD + c * 32 + lg * 8];
      s0 = __builtin_amdgcn_mfma_f32_16x16x32_bf16(qf[c], k0, s0, 0, 0, 0);
      s1 = __builtin_amdgcn_mfma_f32_16x16x32_bf16(qf[c], k1, s1, 0, 0, 0);
      s2 = __builtin_amdgcn_mfma_f32_16x16x32_bf16(qf[c], k2, s2, 0, 0, 0);
      s3 = __builtin_amdgcn_mfma_f32_16x16x32_bf16(qf[c], k3, s3, 0, 0, 0);
    }
    float pv0[4], pv1[4], pv2[4], pv3[4], mx[4];
    bool need = false;
#pragma unroll
    for (int r = 0; r < 4; ++r) {
      const int qr = q0 + lg * 4 + r;
      float a0 = (kv0 +      lr > qr) ? -1e30f : s0[r] * scl;
      float a1 = (kv0 + 16 + lr > qr) ? -1e30f : s1[r] * scl;
      float a2 = (kv0 + 32 + lr > qr) ? -1e30f : s2[r] * scl;
      float a3 = (kv0 + 48 + lr > qr) ? -1e30f : s3[r] * scl;
      pv0[r] = a0; pv1[r] = a1; pv2[r] = a2; pv3[r] = a3;
      float m = fmaxf(fmaxf(a0, a1), fmaxf(a2, a3));
#pragma unroll
      for (int mk = 1; mk < 16; mk <<= 1) m = fmaxf(m, __shfl_xor(m, mk, 64));
      mx[r] = m;
      need = need || (m > mrow[r] + 8.f);
    }
    if (__ballot(need)) {
#pragma unroll
      for (int r = 0; r < 4; ++r) {
        float mnew = fmaxf(mrow[r], mx[r]);
        float resc = __expf(mrow[r] - mnew);
        lrow[r] *= resc;
#pragma unroll
        for (int d = 0; d < 5; ++d) oacc[d][r] *= resc;
        mrow[r] = mnew;
      }
    }
#pragma unroll
    for (int r = 0; r < 4; ++r) {
      const int row = lg * 4 + r;
      const int swz = (row & 7) << 4;
      float p0 = __expf(pv0[r] - mrow[r]);
      float p1 = __expf(pv1[r] - mrow[r]);
      float p2 = __expf(pv2[r] - mrow[r]);
      float p3 = __expf(pv3[r] - mrow[r]);
      *(unsigned short*)(Pb + row * 128 + ((( 0 + lr) * 2) ^ swz)) = f2bf(p0);
      *(unsigned short*)(Pb + row * 128 + (((16 + lr) * 2) ^ swz)) = f2bf(p1);
      *(unsigned short*)(Pb + row * 128 + (((32 + lr) * 2) ^ swz)) = f2bf(p2);
      *(unsigned short*)(Pb + row * 128 + (((48 + lr) * 2) ^ swz)) = f2bf(p3);
      float rs = (p0 + p1) + (p2 + p3);
#pragma unroll
      for (int mk = 1; mk < 16; mk <<= 1) rs += __shfl_xor(rs, mk, 64);
      lrow[r] += rs;
    }
    asm volatile("s_waitcnt lgkmcnt(0)" ::: "memory");
    const int rswz = (lr & 7) << 4;
    bf16x8 pa0 = *(const bf16x8*)(Pb + lr * 128 + ((lg * 16) ^ rswz));
    bf16x8 pa1 = *(const bf16x8*)(Pb + lr * 128 + ((64 + lg * 16) ^ rswz));
#pragma unroll
    for (int d = 0; d < 5; ++d) {
      bf16x8 v0 = *(const bf16x8*)&Vh[(size_t)(d * 16 + lr) * SS + kv0 + lg * 8];
      bf16x8 v1 = *(const bf16x8*)&Vh[(size_t)(d * 16 + lr) * SS + kv0 + 32 + lg * 8];
      oacc[d] = __builtin_amdgcn_mfma_f32_16x16x32_bf16(pa0, v0, oacc[d], 0, 0, 0);
      oacc[d] = __builtin_amdgcn_mfma_f32_16x16x32_bf16(pa1, v1, oacc[d], 0, 0, 0);
    }
  }
  const int b = bh >> 5, h = bh & 31;
#pragma unroll
  for (int r = 0; r < 4; ++r) {
    const int qr = q0 + lg * 4 + r;
    const float inv = 1.f / lrow[r];
#pragma unroll
    for (int d = 0; d < 5; ++d)
      O[(size_t)(b * SS + qr) * DD + h * DHH + d * 16 + lr] = f2bf(oacc[d][r] * inv);
  }
}

// ---------------- 128x128 GEMM, 4 waves, BK=32, double-buffered, 4 blocks/CU ----------------
__device__ __forceinline__ float gelu_f(float x) {
  float x3 = x * x * x;
  return 0.5f * x * (1.f + tanhf(0.7978845608028654f * (x + 0.044715f * x3)));
}

// LDS (32 KB): A [2 buf][128][32] bf16 at 0; B same at 16384.
// MODE 0: out bf16 = C + bias ; MODE 2: bf16 gelu(C+bias) ; MODE 3: fp32 C+bias+bf16(addb)+addf
template <int MODE>
__global__ __launch_bounds__(256, 4) void gemm128(const unsigned short* __restrict__ A,
                                                  const unsigned short* __restrict__ Bt,
                                                  const float* __restrict__ bias,
                                                  void* __restrict__ Cout,
                                                  const unsigned short* __restrict__ addb,
                                                  const float* __restrict__ addf,
                                                  int M, int N, int K, int nbx) {
  __shared__ __align__(16) char lds[32768];

  // bijective XCD swizzle (m204)
  const int nwg = gridDim.x;
  const int orig = blockIdx.x;
  const int qq = nwg >> 3, rr = nwg & 7;
  const int xcd = orig & 7, loc = orig >> 3;
  const int swz = (xcd < rr ? xcd * (qq + 1) : rr * (qq + 1) + (xcd - rr) * qq) + loc;
  const int by = swz / nbx, bx = swz % nbx;
  const int m0 = by * 128, n0 = bx * 128;

  const int tid = threadIdx.x;
  const int w = tid >> 6, lane = tid & 63;
  const int lr = lane & 15, lg = lane >> 4;
  const int wm = w & 1, wn = w >> 1;

  // staging: per wave, rows w*32..w*32+31 of each 128x32 tile (2 gl_lds each for A and B).
  // linear LDS dest; source k-slot pre-swizzled so read-side XOR sees linear data.
  const int srow = w * 32 + (lane >> 2);
  const int skc  = ((lane & 3) ^ ((lane >> 3) & 3)) * 8;
  const unsigned short* aSrc = A  + (size_t)(m0 + srow) * K + skc;
  const unsigned short* bSrc = Bt + (size_t)(n0 + srow) * K + skc;
  const int sdst = w * 2048;

  // fragment read: row stride 64 B; swizzled 16B slot = lg ^ ((lr>>1)&3)  (0-conflict, verified r3/r4)
  const int fsw = (lg ^ ((lr >> 1) & 3)) << 4;
  const int arowb = (wm * 64 + lr) * 64;  // + m*1024
  const int browb = (wn * 64 + lr) * 64;  // + n*1024

  f32x4 acc[4][4];
#pragma unroll
  for (int i = 0; i < 4; ++i)
#pragma unroll
    for (int j = 0; j < 4; ++j) acc[i][j] = (f32x4){0.f, 0.f, 0.f, 0.f};

  const int nt = K >> 5;

#define STAGE(t, b)                                                       \
  { const unsigned short* _a = aSrc + (size_t)(t) * 32;                   \
    const unsigned short* _b = bSrc + (size_t)(t) * 32;                   \
    gl_lds16(_a,                lds + (b) * 8192 + sdst);                 \
    gl_lds16(_a + (size_t)16 * K, lds + (b) * 8192 + sdst + 1024);        \
    gl_lds16(_b,                lds + 16384 + (b) * 8192 + sdst);         \
    gl_lds16(_b + (size_t)16 * K, lds + 16384 + (b) * 8192 + sdst + 1024); }
#define LDA(b, m) (*(const bf16x8*)(lds + (b) * 8192 + arowb + (m) * 1024 + fsw))
#define LDB(b, n) (*(const bf16x8*)(lds + 16384 + (b) * 8192 + browb + (n) * 1024 + fsw))

  STAGE(0, 0);
  __syncthreads();

  for (int t = 0; t < nt; ++t) {
    const int cur = t & 1;
    if (t + 1 < nt) STAGE(t + 1, cur ^ 1);
    bf16x8 bv0 = LDB(cur, 0), bv1 = LDB(cur, 1), bv2 = LDB(cur, 2), bv3 = LDB(cur, 3);
    bf16x8 a0 = LDA(cur, 0), a1 = LDA(cur, 1);
    acc[0][0] = __builtin_amdgcn_mfma_f32_16x16x32_bf16(a0, bv0, acc[0][0], 0, 0, 0);
    acc[0][1] = __builtin_amdgcn_mfma_f32_16x16x32_bf16(a0, bv1, acc[0][1], 0, 0, 0);
    acc[0][2] = __builtin_amdgcn_mfma_f32_16x16x32_bf16(a0, bv2, acc[0][2], 0, 0, 0);
    acc[0][3] = __builtin_amdgcn_mfma_f32_16x16x32_bf16(a0, bv3, acc[0][3], 0, 0, 0);
    acc[1][0] = __builtin_amdgcn_mfma_f32_16x16x32_bf16(a1, bv0, acc[1][0], 0, 0, 0);
    acc[1][1] = __builtin_amdgcn_mfma_f32_16x16x32_bf16(a1, bv1, acc[1][1], 0, 0, 0);
    acc[1][2] = __builtin_amdgcn_mfma_f32_16x16x32_bf16(a1, bv2, acc[1][2], 0, 0, 0);
    acc[1][3] = __builtin_amdgcn_mfma_f32_16x16x32_bf16(a1, bv3, acc[1][3], 0, 0, 0);
    bf16x8 a2 = LDA(cur, 2), a3 = LDA(cur, 3);
    acc[2][0] = __builtin_amdgcn_mfma_f32_16x16x32_bf16(a2, bv0, acc[2][0], 0, 0, 0);
    acc[2][1] = __builtin_amdgcn_mfma_f32_16x16x32_bf16(a2, bv1, acc[2][1], 0, 0, 0);
    acc[2][2] = __builtin_amdgcn_mfma_f32_16x16x32_bf16(a2, bv2, acc[2][2], 0, 0, 0);
    acc[2][3] = __builtin_amdgcn_mfma_f32_16x16x32_bf16(a2, bv3, acc[2][3], 0, 0, 0);
    acc[3][0] = __builtin_amdgcn_mfma_f32_16x16x32_bf16(a3, bv0, acc[3][0], 0, 0, 0);
    acc[3][1] = __builtin_amdgcn_mfma_f32_16x16x32_bf16(a3, bv1, acc[3][1], 0, 0, 0);
    acc[3][2] = __builtin_amdgcn_mfma_f32_16x16x32_bf16(a3, bv2, acc[3][2], 0, 0, 0);
    acc[3][3] = __builtin_amdgcn_mfma_f32_16x16x32_bf16(a3, bv3, acc[3][3], 0, 0, 0);
    __syncthreads();  // drains vmcnt (next tile staged) + syncs buffer swap
  }
#undef STAGE
#undef LDA
#undef LDB

  // epilogue
#pragma unroll
  for (int m = 0; m < 4; ++m) {
    const int rb = m0 + wm * 64 + m * 16 + lg * 4;
#pragma unroll
    for (int n = 0; n < 4; ++n) {
      const int col = n0 + wn * 64 + n * 16 + lr;
      const float bv = bias[col];
#pragma unroll
      for (int r = 0; r < 4; ++r) {
        const size_t idx = (size_t)(rb + r) * N + col;
        float v = acc[m][n][r] + bv;
        if (MODE == 2) v = gelu_f(v);
        if (MODE == 3) {
          ((float*)Cout)[idx] = v + bf2f(addb[idx]) + addf[idx];
        } else {
          ((unsigned short*)Cout)[idx] = f2bf(v);
        }
      }
    }
  }
}

extern "C" void kernel_launch(void* const* d_in, const int* in_sizes, int n_in,
                              void* d_out, int out_size, void* d_ws, size_t ws_size,
                              hipStream_t stream) {
  (void)in_sizes; (void)n_in; (void)out_size; (void)ws_size;
  const float* hidden = (const float*)d_in[1];
  const float* ln_g = (const float*)d_in[2];
  const float* ln_b = (const float*)d_in[3];
  const float* wqkv = (const float*)d_in[4];
  const float* bqkv = (const float*)d_in[5];
  const float* wout = (const float*)d_in[6];
  const float* bout = (const float*)d_in[7];
  const float* wfc1 = (const float*)d_in[8];
  const float* bfc1 = (const float*)d_in[9];
  const float* wfc2 = (const float*)d_in[10];
  const float* bfc2 = (const float*)d_in[11];
  float* out = (float*)d_out;

  char* ws = (char*)d_ws;
  size_t off = 0;
  auto alloc = [&](size_t bytes) -> void* {
    void* p = ws + off;
    off += (bytes + 255) & ~(size_t)255;
    return p;
  };
  unsigned short* wqkvT = (unsigned short*)alloc((size_t)3 * DD * DD * 2);
  unsigned short* woutT = (unsigned short*)alloc((size_t)DD * DD * 2);
  unsigned short* wfc1T = (unsigned short*)alloc((size_t)NII * DD * 2);
  unsigned short* wfc2T = (unsigned short*)alloc((size_t)DD * NII * 2);
  unsigned short* xln   = (unsigned short*)alloc((size_t)NTOK * DD * 2);
  unsigned short* regA  = (unsigned short*)alloc((size_t)NTOK * NII * 2);  // qkv, then h1
  unsigned short* Qp    = (unsigned short*)alloc((size_t)2 * HH * SS * DPAD * 2);  // then attn_proj
  unsigned short* Kp    = (unsigned short*)alloc((size_t)2 * HH * SS * DPAD * 2);
  unsigned short* Vt    = (unsigned short*)alloc((size_t)2 * HH * DHH * SS * 2);
  unsigned short* Obuf  = (unsigned short*)alloc((size_t)NTOK * DD * 2);
  unsigned short* qkvbuf   = regA;
  unsigned short* h1       = regA;
  unsigned short* attnproj = Qp;

  wt_transpose<<<dim3(3 * DD / 32, DD / 32), 256, 0, stream>>>(wqkv, wqkvT, DD, 3 * DD);
  wt_transpose<<<dim3(DD / 32, DD / 32), 256, 0, stream>>>(wout, woutT, DD, DD);
  wt_transpose<<<dim3(NII / 32, DD / 32), 256, 0, stream>>>(wfc1, wfc1T, DD, NII);
  wt_transpose<<<dim3(DD / 32, NII / 32), 256, 0, stream>>>(wfc2, wfc2T, NII, DD);
  ln_kernel<<<NTOK, 256, 0, stream>>>(hidden, ln_g, ln_b, xln);
  gemm128<0><<<dim3((3 * DD / 128) * (NTOK / 128)), 256, 0, stream>>>(
      xln, wqkvT, bqkv, qkvbuf, nullptr, nullptr, NTOK, 3 * DD, DD, 3 * DD / 128);
  rope_kernel<<<NTOK, 256, 0, stream>>>(qkvbuf, Qp, Kp, Vt);
  attn_kernel<<<dim3(4096), 128, 0, stream>>>(Qp, Kp, Vt, Obuf);
  gemm128<0><<<dim3((DD / 128) * (NTOK / 128)), 256, 0, stream>>>(
      Obuf, woutT, bout, attnproj, nullptr, nullptr, NTOK, DD, DD, DD / 128);
  gemm128<2><<<dim3((NII / 128) * (NTOK / 128)), 256, 0, stream>>>(
      xln, wfc1T, bfc1, h1, nullptr, nullptr, NTOK, NII, DD, NII / 128);
  gemm128<3><<<dim3((DD / 128) * (NTOK / 128)), 256, 0, stream>>>(
      h1, wfc2T, bfc2, out, attnproj, hidden, NTOK, DD, NII, DD / 128);
}

// Round 6
// 1333.751 us; speedup vs baseline: 1.0077x; 1.0077x over previous
//
#include <hip/hip_runtime.h>

#define SS   2048
#define DD   2560
#define HH   32
#define DHH  80
#define DPAD 96
#define NII  10240
#define NTOK 4096

typedef __attribute__((ext_vector_type(8))) __bf16 bf16x8;
typedef __attribute__((ext_vector_type(4))) float  f32x4;

__device__ __forceinline__ float bf2f(unsigned short h) {
  union { unsigned u; float f; } c; c.u = ((unsigned)h) << 16; return c.f;
}
__device__ __forceinline__ unsigned short f2bf(float f) {
  union { float f; unsigned u; } c; c.f = f;
  unsigned r = c.u + 0x7FFFu + ((c.u >> 16) & 1u);
  return (unsigned short)(r >> 16);
}

__device__ __forceinline__ void gl_lds16(const void* gptr, void* lptr) {
  __builtin_amdgcn_global_load_lds((__attribute__((address_space(1))) void*)gptr,
                                   (__attribute__((address_space(3))) void*)lptr,
                                   16, 0, 0);
}

// ---------------- weight transpose: W[K][N] fp32 -> Wt[N][K] bf16 ----------------
__global__ __launch_bounds__(256) void wt_transpose(const float* __restrict__ W,
                                                    unsigned short* __restrict__ Wt,
                                                    int K, int N) {
  __shared__ float tile[32][33];
  const int tx = threadIdx.x & 31, ty = threadIdx.x >> 5;
  const int n0 = blockIdx.x * 32, k0 = blockIdx.y * 32;
#pragma unroll
  for (int i = 0; i < 32; i += 8)
    tile[ty + i][tx] = W[(size_t)(k0 + ty + i) * N + n0 + tx];
  __syncthreads();
#pragma unroll
  for (int i = 0; i < 32; i += 8)
    Wt[(size_t)(n0 + ty + i) * K + k0 + tx] = f2bf(tile[tx][ty + i]);
}

// ---------------- LayerNorm: fp32 in -> bf16 out ----------------
__global__ __launch_bounds__(256) void ln_kernel(const float* __restrict__ X,
                                                 const float* __restrict__ G,
                                                 const float* __restrict__ Bb,
                                                 unsigned short* __restrict__ Xo) {
  const int row = blockIdx.x;
  const float4* xr = (const float4*)(X + (size_t)row * DD);
  float s = 0.f, ss = 0.f;
  for (int i = threadIdx.x; i < DD / 4; i += 256) {
    float4 v = xr[i];
    s  += v.x + v.y + v.z + v.w;
    ss += v.x * v.x + v.y * v.y + v.z * v.z + v.w * v.w;
  }
#pragma unroll
  for (int o = 32; o > 0; o >>= 1) { s += __shfl_down(s, o, 64); ss += __shfl_down(ss, o, 64); }
  __shared__ float red[8];
  const int w = threadIdx.x >> 6;
  if ((threadIdx.x & 63) == 0) { red[w] = s; red[4 + w] = ss; }
  __syncthreads();
  if (threadIdx.x == 0) {
    float ts  = red[0] + red[1] + red[2] + red[3];
    float tss = red[4] + red[5] + red[6] + red[7];
    float mu  = ts * (1.f / DD);
    float var = tss * (1.f / DD) - mu * mu;
    red[0] = mu; red[1] = rsqrtf(var + 1e-5f);
  }
  __syncthreads();
  const float mu = red[0], rstd = red[1];
  const float4* gr = (const float4*)G;
  const float4* br = (const float4*)Bb;
  for (int i = threadIdx.x; i < DD / 4; i += 256) {
    float4 v = xr[i], g = gr[i], b = br[i];
    ushort4 o;
    o.x = f2bf((v.x - mu) * rstd * g.x + b.x);
    o.y = f2bf((v.y - mu) * rstd * g.y + b.y);
    o.z = f2bf((v.z - mu) * rstd * g.z + b.z);
    o.w = f2bf((v.w - mu) * rstd * g.w + b.w);
    *(ushort4*)&Xo[(size_t)row * DD + i * 4] = o;
  }
}

// ---------------- RoPE + head-layout ----------------
__global__ __launch_bounds__(256) void rope_kernel(const unsigned short* __restrict__ qkv,
                                                   unsigned short* __restrict__ Qp,
                                                   unsigned short* __restrict__ Kp,
                                                   unsigned short* __restrict__ Vt) {
  const int tok = blockIdx.x;
  const int b = tok / SS, s = tok % SS;
  __shared__ float cs[16], sn[16];
  if (threadIdx.x < 16) {
    float inv = powf(10000.f, -(float)threadIdx.x / 16.f);
    float ang = (float)s * inv;
    cs[threadIdx.x] = cosf(ang);
    sn[threadIdx.x] = sinf(ang);
  }
  __syncthreads();
  const unsigned short* row = qkv + (size_t)tok * (3 * DD);
  for (int idx = threadIdx.x; idx < 2 * HH * DPAD; idx += 256) {
    const int which = idx / (HH * DPAD);
    const int rrem  = idx % (HH * DPAD);
    const int h = rrem / DPAD, d = rrem % DPAD;
    float val = 0.f;
    if (d < DHH) {
      const unsigned short* base = row + which * DD + h * DHH;
      if (d < 16) {
        float x1 = bf2f(base[d]), x2 = bf2f(base[d + 16]);
        val = x1 * cs[d] - x2 * sn[d];
      } else if (d < 32) {
        int i2 = d - 16;
        float x1 = bf2f(base[i2]), x2 = bf2f(base[d]);
        val = x2 * cs[i2] + x1 * sn[i2];
      } else {
        val = bf2f(base[d]);
      }
    }
    unsigned short* outp = which ? Kp : Qp;
    outp[(((size_t)b * HH + h) * SS + s) * DPAD + d] = f2bf(val);
  }
  for (int idx = threadIdx.x; idx < DD; idx += 256) {
    const int h = idx / DHH, d = idx % DHH;
    Vt[(((size_t)b * HH + h) * DHH + d) * SS + s] = row[2 * DD + idx];
  }
}

// ---------------- flash attention (causal), 2-wave blocks, 16 q-rows/wave, KVBLK=64 ----------------
__global__ __launch_bounds__(128) void attn_kernel(const unsigned short* __restrict__ Qp,
                                                   const unsigned short* __restrict__ Kp,
                                                   const unsigned short* __restrict__ Vt,
                                                   unsigned short* __restrict__ O) {
  const int bid = blockIdx.x;
  const int bh = bid & 63;
  const int p = 63 - (bid >> 6);        // heavy first
  const int w = threadIdx.x >> 6;
  const int tile = p * 2 + w;
  const int lane = threadIdx.x & 63;
  const int lr = lane & 15, lg = lane >> 4;
  const int q0 = tile * 16;
  const unsigned short* Qh = Qp + (size_t)bh * SS * DPAD;
  const unsigned short* Kh = Kp + (size_t)bh * SS * DPAD;
  const unsigned short* Vh = Vt + (size_t)bh * DHH * SS;
  __shared__ __align__(16) char Plds[2][2048];
  char* Pb = Plds[w];

  bf16x8 qf[3];
#pragma unroll
  for (int c = 0; c < 3; ++c)
    qf[c] = *(const bf16x8*)&Qh[(size_t)(q0 + lr) * DPAD + c * 32 + lg * 8];

  f32x4 oacc[5];
#pragma unroll
  for (int d = 0; d < 5; ++d) oacc[d] = (f32x4){0.f, 0.f, 0.f, 0.f};
  float mrow[4], lrow[4];
#pragma unroll
  for (int r = 0; r < 4; ++r) { mrow[r] = -1e30f; lrow[r] = 0.f; }

  const float scl = 0.11180339887498949f;
  const int nt = q0 / 64 + 1;
  for (int t = 0; t < nt; ++t) {
    const int kv0 = t * 64;
    f32x4 s0 = (f32x4){0.f, 0.f, 0.f, 0.f};
    f32x4 s1 = (f32x4){0.f, 0.f, 0.f, 0.f};
    f32x4 s2 = (f32x4){0.f, 0.f, 0.f, 0.f};
    f32x4 s3 = (f32x4){0.f, 0.f, 0.f, 0.f};
#pragma unroll
    for (int c = 0; c < 3; ++c) {
      bf16x8 k0 = *(const bf16x8*)&Kh[(size_t)(kv0 +      lr) * DPAD + c * 32 + lg * 8];
      bf16x8 k1 = *(const bf16x8*)&Kh[(size_t)(kv0 + 16 + lr) * DPAD + c * 32 + lg * 8];
      bf16x8 k2 = *(const bf16x8*)&Kh[(size_t)(kv0 + 32 + lr) * DPAD + c * 32 + lg * 8];
      bf16x8 k3 = *(const bf16x8*)&Kh[(size_t)(kv0 + 48 + lr) * DPAD + c * 32 + lg * 8];
      s0 = __builtin_amdgcn_mfma_f32_16x16x32_bf16(qf[c], k0, s0, 0, 0, 0);
      s1 = __builtin_amdgcn_mfma_f32_16x16x32_bf16(qf[c], k1, s1, 0, 0, 0);
      s2 = __builtin_amdgcn_mfma_f32_16x16x32_bf16(qf[c], k2, s2, 0, 0, 0);
      s3 = __builtin_amdgcn_mfma_f32_16x16x32_bf16(qf[c], k3, s3, 0, 0, 0);
    }
    float pv0[4], pv1[4], pv2[4], pv3[4], mx[4];
    bool need = false;
#pragma unroll
    for (int r = 0; r < 4; ++r) {
      const int qr = q0 + lg * 4 + r;
      float a0 = (kv0 +      lr > qr) ? -1e30f : s0[r] * scl;
      float a1 = (kv0 + 16 + lr > qr) ? -1e30f : s1[r] * scl;
      float a2 = (kv0 + 32 + lr > qr) ? -1e30f : s2[r] * scl;
      float a3 = (kv0 + 48 + lr > qr) ? -1e30f : s3[r] * scl;
      pv0[r] = a0; pv1[r] = a1; pv2[r] = a2; pv3[r] = a3;
      float m = fmaxf(fmaxf(a0, a1), fmaxf(a2, a3));
#pragma unroll
      for (int mk = 1; mk < 16; mk <<= 1) m = fmaxf(m, __shfl_xor(m, mk, 64));
      mx[r] = m;
      need = need || (m > mrow[r] + 8.f);
    }
    if (__ballot(need)) {
#pragma unroll
      for (int r = 0; r < 4; ++r) {
        float mnew = fmaxf(mrow[r], mx[r]);
        float resc = __expf(mrow[r] - mnew);
        lrow[r] *= resc;
#pragma unroll
        for (int d = 0; d < 5; ++d) oacc[d][r] *= resc;
        mrow[r] = mnew;
      }
    }
#pragma unroll
    for (int r = 0; r < 4; ++r) {
      const int row = lg * 4 + r;
      const int swz = (row & 7) << 4;
      float p0 = __expf(pv0[r] - mrow[r]);
      float p1 = __expf(pv1[r] - mrow[r]);
      float p2 = __expf(pv2[r] - mrow[r]);
      float p3 = __expf(pv3[r] - mrow[r]);
      *(unsigned short*)(Pb + row * 128 + ((( 0 + lr) * 2) ^ swz)) = f2bf(p0);
      *(unsigned short*)(Pb + row * 128 + (((16 + lr) * 2) ^ swz)) = f2bf(p1);
      *(unsigned short*)(Pb + row * 128 + (((32 + lr) * 2) ^ swz)) = f2bf(p2);
      *(unsigned short*)(Pb + row * 128 + (((48 + lr) * 2) ^ swz)) = f2bf(p3);
      float rs = (p0 + p1) + (p2 + p3);
#pragma unroll
      for (int mk = 1; mk < 16; mk <<= 1) rs += __shfl_xor(rs, mk, 64);
      lrow[r] += rs;
    }
    asm volatile("s_waitcnt lgkmcnt(0)" ::: "memory");
    const int rswz = (lr & 7) << 4;
    bf16x8 pa0 = *(const bf16x8*)(Pb + lr * 128 + ((lg * 16) ^ rswz));
    bf16x8 pa1 = *(const bf16x8*)(Pb + lr * 128 + ((64 + lg * 16) ^ rswz));
#pragma unroll
    for (int d = 0; d < 5; ++d) {
      bf16x8 v0 = *(const bf16x8*)&Vh[(size_t)(d * 16 + lr) * SS + kv0 + lg * 8];
      bf16x8 v1 = *(const bf16x8*)&Vh[(size_t)(d * 16 + lr) * SS + kv0 + 32 + lg * 8];
      oacc[d] = __builtin_amdgcn_mfma_f32_16x16x32_bf16(pa0, v0, oacc[d], 0, 0, 0);
      oacc[d] = __builtin_amdgcn_mfma_f32_16x16x32_bf16(pa1, v1, oacc[d], 0, 0, 0);
    }
  }
  const int b = bh >> 5, h = bh & 31;
#pragma unroll
  for (int r = 0; r < 4; ++r) {
    const int qr = q0 + lg * 4 + r;
    const float inv = 1.f / lrow[r];
#pragma unroll
    for (int d = 0; d < 5; ++d)
      O[(size_t)(b * SS + qr) * DD + h * DHH + d * 16 + lr] = f2bf(oacc[d][r] * inv);
  }
}

// ---------------- 256x256 GEMM, 8 waves (2Mx4N), wave=128x64, BK=64, dbuf ----------------
__device__ __forceinline__ float gelu_f(float x) {
  float x3 = x * x * x;
  return 0.5f * x * (1.f + tanhf(0.7978845608028654f * (x + 0.044715f * x3)));
}

// LDS (128 KB): A: [2 buf][256 rows][64 k] bf16 at buf*32768; B same at +65536.
// Row = 128 B = 8 slots of 16 B; slot stored at  slot ^ (row & 7)  (2-way banks, free).
// MODE 0: out bf16 = C + bias ; MODE 2: bf16 gelu(C+bias) ; MODE 3: fp32 C+bias+bf16(addb)+addf
template <int MODE>
__global__ __launch_bounds__(512, 2) void gemm256(const unsigned short* __restrict__ A,
                                                  const unsigned short* __restrict__ Bt,
                                                  const float* __restrict__ bias,
                                                  void* __restrict__ Cout,
                                                  const unsigned short* __restrict__ addb,
                                                  const float* __restrict__ addf,
                                                  int M, int N, int K, int nbx) {
  __shared__ __align__(16) char lds[131072];

  // bijective XCD swizzle (m204)
  const int nwg = gridDim.x;
  const int orig = blockIdx.x;
  const int qq = nwg >> 3, rr = nwg & 7;
  const int xcd = orig & 7, loc = orig >> 3;
  const int swz = (xcd < rr ? xcd * (qq + 1) : rr * (qq + 1) + (xcd - rr) * qq) + loc;
  const int by = swz / nbx, bx = swz % nbx;
  const int m0 = by * 256, n0 = bx * 256;

  const int tid = threadIdx.x;
  const int w = tid >> 6, lane = tid & 63;
  const int lr = lane & 15, lg = lane >> 4;
  const int wm = w >> 2, wn = w & 3;   // 2M x 4N; wave tile 128x64

  // ---- staging (pre-swizzled source, linear LDS dest; rule #21 involution) ----
  const int l8 = lane >> 3, l7 = lane & 7;
  const unsigned short* aStg = A  + (size_t)(m0 + w * 32 + l8) * K + ((l7 ^ l8) * 8);
  const unsigned short* bStg = Bt + (size_t)(n0 + w * 32 + l8) * K + ((l7 ^ l8) * 8);
  const int stgDst = w * 4096;  // + i*1024 ; each issue covers 8 rows x 128 B

  // ---- fragment read offsets: row*128 + (slot ^ (row&7))*16, slot = kh*4+lg ----
  const int s0 = lg ^ (lr & 7);
  const int a0 = (wm * 128 + lr) * 128 + (s0 << 4);
  const int a1 = (wm * 128 + lr) * 128 + ((s0 << 4) ^ 64);
  const int b0 = (wn * 64 + lr) * 128 + (s0 << 4);
  const int b1 = (wn * 64 + lr) * 128 + ((s0 << 4) ^ 64);

  f32x4 acc[8][4];
#pragma unroll
  for (int i = 0; i < 8; ++i)
#pragma unroll
    for (int j = 0; j < 4; ++j) acc[i][j] = (f32x4){0.f, 0.f, 0.f, 0.f};

  const int nsteps = K >> 6;  // K-steps of 64 (always even here: 40 or 160)

#define STGA(DST, i) gl_lds16(aStg + (size_t)(i) * 8 * K, lds + (DST) + stgDst + (i) * 1024)
#define STGB(DST, i) gl_lds16(bStg + (size_t)(i) * 8 * K, lds + 65536 + (DST) + stgDst + (i) * 1024)
#define RDA(CUR, m, kh) (*(const bf16x8*)(lds + (CUR) + (m) * 2048 + ((kh) ? a1 : a0)))
#define RDB(CUR, n, kh) (*(const bf16x8*)(lds + 65536 + (CUR) + (n) * 2048 + ((kh) ? b1 : b0)))

#define GSTEP(CUR, NXT, scur)                                                            \
  {                                                                                      \
    const bool stg = (scur) + 1 < nsteps;                                                \
    bf16x8 av[4][2], bv0[2][2];                                                          \
    _Pragma("unroll") for (int m = 0; m < 4; ++m) {                                      \
      av[m][0] = RDA(CUR, m, 0); av[m][1] = RDA(CUR, m, 1); }                            \
    _Pragma("unroll") for (int n = 0; n < 2; ++n) {                                      \
      bv0[n][0] = RDB(CUR, n, 0); bv0[n][1] = RDB(CUR, n, 1); }                          \
    if (stg) { STGA(NXT, 0); STGA(NXT, 1); STGA(NXT, 2); STGA(NXT, 3); }                 \
    __builtin_amdgcn_s_barrier();                                                        \
    __builtin_amdgcn_s_setprio(1);                                                       \
    _Pragma("unroll") for (int kh = 0; kh < 2; ++kh)                                     \
    _Pragma("unroll") for (int m = 0; m < 4; ++m)                                        \
    _Pragma("unroll") for (int n = 0; n < 2; ++n)                                        \
      acc[m][n] = __builtin_amdgcn_mfma_f32_16x16x32_bf16(av[m][kh], bv0[n][kh],         \
                                                          acc[m][n], 0, 0, 0);           \
    __builtin_amdgcn_s_setprio(0);                                                       \
    __builtin_amdgcn_s_barrier();                                                        \
    bf16x8 av2[4][2];                                                                    \
    _Pragma("unroll") for (int m = 0; m < 4; ++m) {                                      \
      av2[m][0] = RDA(CUR, 4 + m, 0); av2[m][1] = RDA(CUR, 4 + m, 1); }                  \
    if (stg) { STGB(NXT, 0); STGB(NXT, 1); STGB(NXT, 2); STGB(NXT, 3); }                 \
    __builtin_amdgcn_s_barrier();                                                        \
    __builtin_amdgcn_s_setprio(1);                                                       \
    _Pragma("unroll") for (int kh = 0; kh < 2; ++kh)                                     \
    _Pragma("unroll") for (int m = 0; m < 4; ++m)                                        \
    _Pragma("unroll") for (int n = 0; n < 2; ++n)                                        \
      acc[4 + m][n] = __builtin_amdgcn_mfma_f32_16x16x32_bf16(av2[m][kh], bv0[n][kh],    \
                                                              acc[4 + m][n], 0, 0, 0);   \
    __builtin_amdgcn_s_setprio(0);                                                       \
    __builtin_amdgcn_s_barrier();                                                        \
    bf16x8 bv1[2][2];                                                                    \
    _Pragma("unroll") for (int n = 0; n < 2; ++n) {                                      \
      bv1[n][0] = RDB(CUR, 2 + n, 0); bv1[n][1] = RDB(CUR, 2 + n, 1); }                  \
    __builtin_amdgcn_s_barrier();                                                        \
    __builtin_amdgcn_s_setprio(1);                                                       \
    _Pragma("unroll") for (int kh = 0; kh < 2; ++kh)                                     \
    _Pragma("unroll") for (int m = 0; m < 4; ++m)                                        \
    _Pragma("unroll") for (int n = 0; n < 2; ++n)                                        \
      acc[m][2 + n] = __builtin_amdgcn_mfma_f32_16x16x32_bf16(av[m][kh], bv1[n][kh],     \
                                                              acc[m][2 + n], 0, 0, 0);   \
    __builtin_amdgcn_s_setprio(0);                                                       \
    __builtin_amdgcn_s_barrier();                                                        \
    _Pragma("unroll") for (int m = 0; m < 4; ++m) {                                      \
      av2[m][0] = RDA(CUR, 4 + m, 0); av2[m][1] = RDA(CUR, 4 + m, 1); }                  \
    __builtin_amdgcn_s_barrier();                                                        \
    __builtin_amdgcn_s_setprio(1);                                                       \
    _Pragma("unroll") for (int kh = 0; kh < 2; ++kh)                                     \
    _Pragma("unroll") for (int m = 0; m < 4; ++m)                                        \
    _Pragma("unroll") for (int n = 0; n < 2; ++n)                                        \
      acc[4 + m][2 + n] = __builtin_amdgcn_mfma_f32_16x16x32_bf16(av2[m][kh],            \
                                          bv1[n][kh], acc[4 + m][2 + n], 0, 0, 0);       \
    __builtin_amdgcn_s_setprio(0);                                                       \
    asm volatile("s_waitcnt vmcnt(0)" ::: "memory");                                     \
    __builtin_amdgcn_s_barrier();                                                        \
    __builtin_amdgcn_sched_barrier(0);                                                   \
    aStg += 64; bStg += 64;                                                              \
  }

  // prologue: stage step 0 into buf0; loads were just issued -> drain once
  STGA(0, 0); STGA(0, 1); STGA(0, 2); STGA(0, 3);
  STGB(0, 0); STGB(0, 1); STGB(0, 2); STGB(0, 3);
  aStg += 64; bStg += 64;
  asm volatile("s_waitcnt vmcnt(0)" ::: "memory");
  __builtin_amdgcn_s_barrier();
  __builtin_amdgcn_sched_barrier(0);

  for (int s = 0; s < nsteps; s += 2) {
    GSTEP(0, 32768, s);
    GSTEP(32768, 0, s + 1);
  }
#undef GSTEP
#undef STGA
#undef STGB
#undef RDA
#undef RDB

  // epilogue
#pragma unroll
  for (int m = 0; m < 8; ++m) {
    const int rb = m0 + wm * 128 + m * 16 + lg * 4;
#pragma unroll
    for (int n = 0; n < 4; ++n) {
      const int col = n0 + wn * 64 + n * 16 + lr;
      const float bv = bias[col];
#pragma unroll
      for (int r = 0; r < 4; ++r) {
        const size_t idx = (size_t)(rb + r) * N + col;
        float v = acc[m][n][r] + bv;
        if (MODE == 2) v = gelu_f(v);
        if (MODE == 3) {
          ((float*)Cout)[idx] = v + bf2f(addb[idx]) + addf[idx];
        } else {
          ((unsigned short*)Cout)[idx] = f2bf(v);
        }
      }
    }
  }
}

extern "C" void kernel_launch(void* const* d_in, const int* in_sizes, int n_in,
                              void* d_out, int out_size, void* d_ws, size_t ws_size,
                              hipStream_t stream) {
  (void)in_sizes; (void)n_in; (void)out_size; (void)ws_size;
  const float* hidden = (const float*)d_in[1];
  const float* ln_g = (const float*)d_in[2];
  const float* ln_b = (const float*)d_in[3];
  const float* wqkv = (const float*)d_in[4];
  const float* bqkv = (const float*)d_in[5];
  const float* wout = (const float*)d_in[6];
  const float* bout = (const float*)d_in[7];
  const float* wfc1 = (const float*)d_in[8];
  const float* bfc1 = (const float*)d_in[9];
  const float* wfc2 = (const float*)d_in[10];
  const float* bfc2 = (const float*)d_in[11];
  float* out = (float*)d_out;

  char* ws = (char*)d_ws;
  size_t off = 0;
  auto alloc = [&](size_t bytes) -> void* {
    void* p = ws + off;
    off += (bytes + 255) & ~(size_t)255;
    return p;
  };
  unsigned short* wqkvT = (unsigned short*)alloc((size_t)3 * DD * DD * 2);
  unsigned short* woutT = (unsigned short*)alloc((size_t)DD * DD * 2);
  unsigned short* wfc1T = (unsigned short*)alloc((size_t)NII * DD * 2);
  unsigned short* wfc2T = (unsigned short*)alloc((size_t)DD * NII * 2);
  unsigned short* xln   = (unsigned short*)alloc((size_t)NTOK * DD * 2);
  unsigned short* regA  = (unsigned short*)alloc((size_t)NTOK * NII * 2);  // qkv, then h1
  unsigned short* Qp    = (unsigned short*)alloc((size_t)2 * HH * SS * DPAD * 2);  // then attn_proj
  unsigned short* Kp    = (unsigned short*)alloc((size_t)2 * HH * SS * DPAD * 2);
  unsigned short* Vt    = (unsigned short*)alloc((size_t)2 * HH * DHH * SS * 2);
  unsigned short* Obuf  = (unsigned short*)alloc((size_t)NTOK * DD * 2);
  unsigned short* qkvbuf   = regA;
  unsigned short* h1       = regA;
  unsigned short* attnproj = Qp;

  wt_transpose<<<dim3(3 * DD / 32, DD / 32), 256, 0, stream>>>(wqkv, wqkvT, DD, 3 * DD);
  wt_transpose<<<dim3(DD / 32, DD / 32), 256, 0, stream>>>(wout, woutT, DD, DD);
  wt_transpose<<<dim3(NII / 32, DD / 32), 256, 0, stream>>>(wfc1, wfc1T, DD, NII);
  wt_transpose<<<dim3(DD / 32, NII / 32), 256, 0, stream>>>(wfc2, wfc2T, NII, DD);
  ln_kernel<<<NTOK, 256, 0, stream>>>(hidden, ln_g, ln_b, xln);
  gemm256<0><<<dim3((3 * DD / 256) * (NTOK / 256)), 512, 0, stream>>>(
      xln, wqkvT, bqkv, qkvbuf, nullptr, nullptr, NTOK, 3 * DD, DD, 3 * DD / 256);
  rope_kernel<<<NTOK, 256, 0, stream>>>(qkvbuf, Qp, Kp, Vt);
  attn_kernel<<<dim3(4096), 128, 0, stream>>>(Qp, Kp, Vt, Obuf);
  gemm256<0><<<dim3((DD / 256) * (NTOK / 256)), 512, 0, stream>>>(
      Obuf, woutT, bout, attnproj, nullptr, nullptr, NTOK, DD, DD, DD / 256);
  gemm256<2><<<dim3((NII / 256) * (NTOK / 256)), 512, 0, stream>>>(
      xln, wfc1T, bfc1, h1, nullptr, nullptr, NTOK, NII, DD, NII / 256);
  gemm256<3><<<dim3((DD / 256) * (NTOK / 256)), 512, 0, stream>>>(
      h1, wfc2T, bfc2, out, attnproj, hidden, NTOK, DD, NII, DD / 256);
}

// Round 8
// 1308.308 us; speedup vs baseline: 1.0273x; 1.0194x over previous
//
#include <hip/hip_runtime.h>

#define SS   2048
#define DD   2560
#define HH   32
#define DHH  80
#define DPAD 96
#define NII  10240
#define NTOK 4096

typedef __attribute__((ext_vector_type(8))) __bf16 bf16x8;
typedef __attribute__((ext_vector_type(4))) float  f32x4;

__device__ __forceinline__ float bf2f(unsigned short h) {
  union { unsigned u; float f; } c; c.u = ((unsigned)h) << 16; return c.f;
}
__device__ __forceinline__ unsigned short f2bf(float f) {
  union { float f; unsigned u; } c; c.f = f;
  unsigned r = c.u + 0x7FFFu + ((c.u >> 16) & 1u);
  return (unsigned short)(r >> 16);
}

__device__ __forceinline__ void gl_lds16(const void* gptr, void* lptr) {
  __builtin_amdgcn_global_load_lds((__attribute__((address_space(1))) void*)gptr,
                                   (__attribute__((address_space(3))) void*)lptr,
                                   16, 0, 0);
}

// ---------------- weight transpose: W[K][N] fp32 -> Wt[N][K] bf16 ----------------
__global__ __launch_bounds__(256) void wt_transpose(const float* __restrict__ W,
                                                    unsigned short* __restrict__ Wt,
                                                    int K, int N) {
  __shared__ float tile[32][33];
  const int tx = threadIdx.x & 31, ty = threadIdx.x >> 5;
  const int n0 = blockIdx.x * 32, k0 = blockIdx.y * 32;
#pragma unroll
  for (int i = 0; i < 32; i += 8)
    tile[ty + i][tx] = W[(size_t)(k0 + ty + i) * N + n0 + tx];
  __syncthreads();
#pragma unroll
  for (int i = 0; i < 32; i += 8)
    Wt[(size_t)(n0 + ty + i) * K + k0 + tx] = f2bf(tile[tx][ty + i]);
}

// ---------------- LayerNorm: fp32 in -> bf16 out ----------------
__global__ __launch_bounds__(256) void ln_kernel(const float* __restrict__ X,
                                                 const float* __restrict__ G,
                                                 const float* __restrict__ Bb,
                                                 unsigned short* __restrict__ Xo) {
  const int row = blockIdx.x;
  const float4* xr = (const float4*)(X + (size_t)row * DD);
  float s = 0.f, ss = 0.f;
  for (int i = threadIdx.x; i < DD / 4; i += 256) {
    float4 v = xr[i];
    s  += v.x + v.y + v.z + v.w;
    ss += v.x * v.x + v.y * v.y + v.z * v.z + v.w * v.w;
  }
#pragma unroll
  for (int o = 32; o > 0; o >>= 1) { s += __shfl_down(s, o, 64); ss += __shfl_down(ss, o, 64); }
  __shared__ float red[8];
  const int w = threadIdx.x >> 6;
  if ((threadIdx.x & 63) == 0) { red[w] = s; red[4 + w] = ss; }
  __syncthreads();
  if (threadIdx.x == 0) {
    float ts  = red[0] + red[1] + red[2] + red[3];
    float tss = red[4] + red[5] + red[6] + red[7];
    float mu  = ts * (1.f / DD);
    float var = tss * (1.f / DD) - mu * mu;
    red[0] = mu; red[1] = rsqrtf(var + 1e-5f);
  }
  __syncthreads();
  const float mu = red[0], rstd = red[1];
  const float4* gr = (const float4*)G;
  const float4* br = (const float4*)Bb;
  for (int i = threadIdx.x; i < DD / 4; i += 256) {
    float4 v = xr[i], g = gr[i], b = br[i];
    ushort4 o;
    o.x = f2bf((v.x - mu) * rstd * g.x + b.x);
    o.y = f2bf((v.y - mu) * rstd * g.y + b.y);
    o.z = f2bf((v.z - mu) * rstd * g.z + b.z);
    o.w = f2bf((v.w - mu) * rstd * g.w + b.w);
    *(ushort4*)&Xo[(size_t)row * DD + i * 4] = o;
  }
}

// ---------------- RoPE + head-layout ----------------
__global__ __launch_bounds__(256) void rope_kernel(const unsigned short* __restrict__ qkv,
                                                   unsigned short* __restrict__ Qp,
                                                   unsigned short* __restrict__ Kp,
                                                   unsigned short* __restrict__ Vt) {
  const int tok = blockIdx.x;
  const int b = tok / SS, s = tok % SS;
  __shared__ float cs[16], sn[16];
  if (threadIdx.x < 16) {
    float inv = powf(10000.f, -(float)threadIdx.x / 16.f);
    float ang = (float)s * inv;
    cs[threadIdx.x] = cosf(ang);
    sn[threadIdx.x] = sinf(ang);
  }
  __syncthreads();
  const unsigned short* row = qkv + (size_t)tok * (3 * DD);
  for (int idx = threadIdx.x; idx < 2 * HH * DPAD; idx += 256) {
    const int which = idx / (HH * DPAD);
    const int rrem  = idx % (HH * DPAD);
    const int h = rrem / DPAD, d = rrem % DPAD;
    float val = 0.f;
    if (d < DHH) {
      const unsigned short* base = row + which * DD + h * DHH;
      if (d < 16) {
        float x1 = bf2f(base[d]), x2 = bf2f(base[d + 16]);
        val = x1 * cs[d] - x2 * sn[d];
      } else if (d < 32) {
        int i2 = d - 16;
        float x1 = bf2f(base[i2]), x2 = bf2f(base[d]);
        val = x2 * cs[i2] + x1 * sn[i2];
      } else {
        val = bf2f(base[d]);
      }
    }
    unsigned short* outp = which ? Kp : Qp;
    outp[(((size_t)b * HH + h) * SS + s) * DPAD + d] = f2bf(val);
  }
  for (int idx = threadIdx.x; idx < DD; idx += 256) {
    const int h = idx / DHH, d = idx % DHH;
    Vt[(((size_t)b * HH + h) * DHH + d) * SS + s] = row[2 * DD + idx];
  }
}

// ---------------- flash attention (causal), 2-wave blocks, 16 q-rows/wave, KVBLK=64 ----------------
__global__ __launch_bounds__(128) void attn_kernel(const unsigned short* __restrict__ Qp,
                                                   const unsigned short* __restrict__ Kp,
                                                   const unsigned short* __restrict__ Vt,
                                                   unsigned short* __restrict__ O) {
  const int bid = blockIdx.x;
  const int bh = bid & 63;
  const int p = 63 - (bid >> 6);        // heavy first
  const int w = threadIdx.x >> 6;
  const int tile = p * 2 + w;
  const int lane = threadIdx.x & 63;
  const int lr = lane & 15, lg = lane >> 4;
  const int q0 = tile * 16;
  const unsigned short* Qh = Qp + (size_t)bh * SS * DPAD;
  const unsigned short* Kh = Kp + (size_t)bh * SS * DPAD;
  const unsigned short* Vh = Vt + (size_t)bh * DHH * SS;
  __shared__ __align__(16) char Plds[2][2048];
  char* Pb = Plds[w];

  bf16x8 qf[3];
#pragma unroll
  for (int c = 0; c < 3; ++c)
    qf[c] = *(const bf16x8*)&Qh[(size_t)(q0 + lr) * DPAD + c * 32 + lg * 8];

  f32x4 oacc[5];
#pragma unroll
  for (int d = 0; d < 5; ++d) oacc[d] = (f32x4){0.f, 0.f, 0.f, 0.f};
  float mrow[4], lrow[4];
#pragma unroll
  for (int r = 0; r < 4; ++r) { mrow[r] = -1e30f; lrow[r] = 0.f; }

  const float scl = 0.11180339887498949f;
  const int nt = q0 / 64 + 1;
  for (int t = 0; t < nt; ++t) {
    const int kv0 = t * 64;
    f32x4 s0 = (f32x4){0.f, 0.f, 0.f, 0.f};
    f32x4 s1 = (f32x4){0.f, 0.f, 0.f, 0.f};
    f32x4 s2 = (f32x4){0.f, 0.f, 0.f, 0.f};
    f32x4 s3 = (f32x4){0.f, 0.f, 0.f, 0.f};
#pragma unroll
    for (int c = 0; c < 3; ++c) {
      bf16x8 k0 = *(const bf16x8*)&Kh[(size_t)(kv0 +      lr) * DPAD + c * 32 + lg * 8];
      bf16x8 k1 = *(const bf16x8*)&Kh[(size_t)(kv0 + 16 + lr) * DPAD + c * 32 + lg * 8];
      bf16x8 k2 = *(const bf16x8*)&Kh[(size_t)(kv0 + 32 + lr) * DPAD + c * 32 + lg * 8];
      bf16x8 k3 = *(const bf16x8*)&Kh[(size_t)(kv0 + 48 + lr) * DPAD + c * 32 + lg * 8];
      s0 = __builtin_amdgcn_mfma_f32_16x16x32_bf16(qf[c], k0, s0, 0, 0, 0);
      s1 = __builtin_amdgcn_mfma_f32_16x16x32_bf16(qf[c], k1, s1, 0, 0, 0);
      s2 = __builtin_amdgcn_mfma_f32_16x16x32_bf16(qf[c], k2, s2, 0, 0, 0);
      s3 = __builtin_amdgcn_mfma_f32_16x16x32_bf16(qf[c], k3, s3, 0, 0, 0);
    }
    float pv0[4], pv1[4], pv2[4], pv3[4], mx[4];
    bool need = false;
#pragma unroll
    for (int r = 0; r < 4; ++r) {
      const int qr = q0 + lg * 4 + r;
      float a0 = (kv0 +      lr > qr) ? -1e30f : s0[r] * scl;
      float a1 = (kv0 + 16 + lr > qr) ? -1e30f : s1[r] * scl;
      float a2 = (kv0 + 32 + lr > qr) ? -1e30f : s2[r] * scl;
      float a3 = (kv0 + 48 + lr > qr) ? -1e30f : s3[r] * scl;
      pv0[r] = a0; pv1[r] = a1; pv2[r] = a2; pv3[r] = a3;
      float m = fmaxf(fmaxf(a0, a1), fmaxf(a2, a3));
#pragma unroll
      for (int mk = 1; mk < 16; mk <<= 1) m = fmaxf(m, __shfl_xor(m, mk, 64));
      mx[r] = m;
      need = need || (m > mrow[r] + 8.f);
    }
    if (__ballot(need)) {
#pragma unroll
      for (int r = 0; r < 4; ++r) {
        float mnew = fmaxf(mrow[r], mx[r]);
        float resc = __expf(mrow[r] - mnew);
        lrow[r] *= resc;
#pragma unroll
        for (int d = 0; d < 5; ++d) oacc[d][r] *= resc;
        mrow[r] = mnew;
      }
    }
#pragma unroll
    for (int r = 0; r < 4; ++r) {
      const int row = lg * 4 + r;
      const int swz = (row & 7) << 4;
      float p0 = __expf(pv0[r] - mrow[r]);
      float p1 = __expf(pv1[r] - mrow[r]);
      float p2 = __expf(pv2[r] - mrow[r]);
      float p3 = __expf(pv3[r] - mrow[r]);
      *(unsigned short*)(Pb + row * 128 + ((( 0 + lr) * 2) ^ swz)) = f2bf(p0);
      *(unsigned short*)(Pb + row * 128 + (((16 + lr) * 2) ^ swz)) = f2bf(p1);
      *(unsigned short*)(Pb + row * 128 + (((32 + lr) * 2) ^ swz)) = f2bf(p2);
      *(unsigned short*)(Pb + row * 128 + (((48 + lr) * 2) ^ swz)) = f2bf(p3);
      float rs = (p0 + p1) + (p2 + p3);
#pragma unroll
      for (int mk = 1; mk < 16; mk <<= 1) rs += __shfl_xor(rs, mk, 64);
      lrow[r] += rs;
    }
    asm volatile("s_waitcnt lgkmcnt(0)" ::: "memory");
    const int rswz = (lr & 7) << 4;
    bf16x8 pa0 = *(const bf16x8*)(Pb + lr * 128 + ((lg * 16) ^ rswz));
    bf16x8 pa1 = *(const bf16x8*)(Pb + lr * 128 + ((64 + lg * 16) ^ rswz));
#pragma unroll
    for (int d = 0; d < 5; ++d) {
      bf16x8 v0 = *(const bf16x8*)&Vh[(size_t)(d * 16 + lr) * SS + kv0 + lg * 8];
      bf16x8 v1 = *(const bf16x8*)&Vh[(size_t)(d * 16 + lr) * SS + kv0 + 32 + lg * 8];
      oacc[d] = __builtin_amdgcn_mfma_f32_16x16x32_bf16(pa0, v0, oacc[d], 0, 0, 0);
      oacc[d] = __builtin_amdgcn_mfma_f32_16x16x32_bf16(pa1, v1, oacc[d], 0, 0, 0);
    }
  }
  const int b = bh >> 5, h = bh & 31;
#pragma unroll
  for (int r = 0; r < 4; ++r) {
    const int qr = q0 + lg * 4 + r;
    const float inv = 1.f / lrow[r];
#pragma unroll
    for (int d = 0; d < 5; ++d)
      O[(size_t)(b * SS + qr) * DD + h * DHH + d * 16 + lr] = f2bf(oacc[d][r] * inv);
  }
}

// ---------------- 256x256 GEMM, 8 waves (2Mx4N), BK=64, 8-phase counted-vmcnt (race-free ledger) ----------------
__device__ __forceinline__ float gelu_f(float x) {
  float x3 = x * x * x;
  return 0.5f * x * (1.f + tanhf(0.7978845608028654f * (x + 0.044715f * x3)));
}

// LDS 128 KB: A [buf][Mhalf][128 rows][64 k] bf16 at buf*32768 + half*16384; B same at +65536.
// Row = 128 B = 8 slots; slot stored at (slot ^ (row&7)); staged via pre-swizzled global source.
// Region read windows: buf0.A:{P1,P2} buf0.B:{P1,P3} buf1.A:{P5,P6} buf1.B:{P5,P7}  (avL held in regs; no P4 re-read)
// Stage slots: P1:B(t+1)h1->buf1  P3:A(t+2)h0  P4:A(t+2)h1  P5:B(t+2)h0  P6:B(t+2)h1  P7:A(t+3)h0->buf1  P8:A(t+3)h1+B(t+3)h0->buf1
// vmcnt ledger (2 loads/stage): entry invariant 6 outstanding {A(t+1)h0,A(t+1)h1,B(t+1)h0};
//  P4-end vmcnt(4) completes exactly tile t+1's 4 HTs; P8-end vmcnt(6) completes exactly tile t+2.
template <int MODE>
__global__ __launch_bounds__(512, 2) void gemm256(const unsigned short* __restrict__ A,
                                                  const unsigned short* __restrict__ Bt,
                                                  const float* __restrict__ bias,
                                                  void* __restrict__ Cout,
                                                  const unsigned short* __restrict__ addb,
                                                  const float* __restrict__ addf,
                                                  int M, int N, int K, int nbx) {
  __shared__ __align__(16) char lds[131072];

  // bijective XCD swizzle (m204)
  const int nwg = gridDim.x;
  const int orig = blockIdx.x;
  const int qq = nwg >> 3, rr = nwg & 7;
  const int xcd = orig & 7, loc = orig >> 3;
  const int swz = (xcd < rr ? xcd * (qq + 1) : rr * (qq + 1) + (xcd - rr) * qq) + loc;
  const int by = swz / nbx, bx = swz % nbx;
  const int m0 = by * 256, n0 = bx * 256;

  const int tid = threadIdx.x;
  const int w = tid >> 6, lane = tid & 63;
  const int lr = lane & 15, lg = lane >> 4;
  const int wm = w >> 2, wn = w & 3;   // 2M x 4N; wave tile 128x64

  // staging: half-tile (128 rows x 64k), 16 rows/wave, 2 gl_lds; pre-swizzled source k-slot.
  const int srow = w * 16 + (lane >> 3);
  const int scol = ((lane & 7) ^ ((lane >> 3) & 7)) * 8;
  const unsigned short* pA = A  + (size_t)(m0 + srow) * K + scol;
  const unsigned short* pB = Bt + (size_t)(n0 + srow) * K + scol;
  const int wdst = w * 2048;

  // fragment reads (r6-verified math): half = wm (A) / wn>>1 (B)
  const int rdA = wm * 16384 + lr * 128;
  const int rdB = 65536 + (wn >> 1) * 16384 + ((wn & 1) * 64 + lr) * 128;
  const int sl0 = ((lg) ^ (lr & 7)) << 4;
  const int sl1 = ((4 + lg) ^ (lr & 7)) << 4;

  f32x4 acc[8][4];
#pragma unroll
  for (int i = 0; i < 8; ++i)
#pragma unroll
    for (int j = 0; j < 4; ++j) acc[i][j] = (f32x4){0.f, 0.f, 0.f, 0.f};

  const int nt = K >> 6;  // K-tiles of 64; even for all shapes here (40 / 160)

#define RA(BUF, m, kh) (*(const bf16x8*)(lds + (BUF) + rdA + (m) * 2048 + ((kh) ? sl1 : sl0)))
#define RB(BUF, n, kh) (*(const bf16x8*)(lds + (BUF) + rdB + (n) * 2048 + ((kh) ? sl1 : sl0)))
#define STGA(dt, h, DST)                                                       \
  { const unsigned short* s_ = pA + (size_t)(dt) * 64 + (size_t)(h) * 128 * K; \
    gl_lds16(s_,                 lds + (DST) + wdst);                          \
    gl_lds16(s_ + (size_t)8 * K, lds + (DST) + wdst + 1024); }
#define STGB(dt, h, DST)                                                       \
  { const unsigned short* s_ = pB + (size_t)(dt) * 64 + (size_t)(h) * 128 * K; \
    gl_lds16(s_,                 lds + 65536 + (DST) + wdst);                  \
    gl_lds16(s_ + (size_t)8 * K, lds + 65536 + (DST) + wdst + 1024); }
#define BARR __builtin_amdgcn_s_barrier()
#define LGKM0 { asm volatile("s_waitcnt lgkmcnt(0)" ::: "memory"); __builtin_amdgcn_sched_barrier(0); }
#define MFMA8x2(AV, BV, MB, NB)                                              \
  __builtin_amdgcn_s_setprio(1);                                             \
  _Pragma("unroll") for (int kh_ = 0; kh_ < 2; ++kh_)                        \
  _Pragma("unroll") for (int m_ = 0; m_ < 4; ++m_)                           \
  _Pragma("unroll") for (int n_ = 0; n_ < 2; ++n_)                           \
    acc[(MB) + m_][(NB) + n_] = __builtin_amdgcn_mfma_f32_16x16x32_bf16(     \
        AV[m_][kh_], BV[n_][kh_], acc[(MB) + m_][(NB) + n_], 0, 0, 0);       \
  __builtin_amdgcn_s_setprio(0);

  // ---- prologue: tile0 (4 HT) fully; tile1 {A.h0, A.h1, B.h0} left in flight (6 loads) ----
  STGA(0, 0, 0);
  STGA(0, 1, 16384);
  STGB(0, 0, 0);
  STGB(0, 1, 16384);
  STGA(1, 0, 32768);
  STGA(1, 1, 32768 + 16384);
  STGB(1, 0, 32768);
  asm volatile("s_waitcnt vmcnt(6)" ::: "memory");
  BARR;
  __builtin_amdgcn_sched_barrier(0);

  for (int t = 0; t < nt; t += 2) {
    const bool more = (t + 2 < nt);  // false only on the final iteration (nt even)
    bf16x8 avL[4][2], avH[4][2], bvL[2][2], bvH[2][2];

    // ---- P1 (tile t, buf0): read avL + bvL ; stage B(t+1).h1 -> buf1.B.h1 ----
#pragma unroll
    for (int m_ = 0; m_ < 4; ++m_) { avL[m_][0] = RA(0, m_, 0); avL[m_][1] = RA(0, m_, 1); }
#pragma unroll
    for (int n_ = 0; n_ < 2; ++n_) { bvL[n_][0] = RB(0, n_, 0); bvL[n_][1] = RB(0, n_, 1); }
    STGB(1, 1, 32768 + 16384);
    BARR; LGKM0;
    MFMA8x2(avL, bvL, 0, 0);
    BARR;
    // ---- P2: read avH ; no stage ----
#pragma unroll
    for (int m_ = 0; m_ < 4; ++m_) { avH[m_][0] = RA(0, 4 + m_, 0); avH[m_][1] = RA(0, 4 + m_, 1); }
    BARR; LGKM0;
    MFMA8x2(avH, bvL, 4, 0);
    BARR;
    // ---- P3: read bvH ; stage A(t+2).h0 -> buf0.A.h0 (A last read P2) ----
#pragma unroll
    for (int n_ = 0; n_ < 2; ++n_) { bvH[n_][0] = RB(0, 2 + n_, 0); bvH[n_][1] = RB(0, 2 + n_, 1); }
    if (more) STGA(2, 0, 0);
    BARR; LGKM0;
    MFMA8x2(avH, bvH, 4, 2);
    BARR;
    // ---- P4: no reads (avL, bvH in regs) ; stage A(t+2).h1 ; counted wait ----
    if (more) STGA(2, 1, 16384);
    BARR;
    MFMA8x2(avL, bvH, 0, 2);
    if (more) { asm volatile("s_waitcnt vmcnt(4)" ::: "memory"); }
    else      { asm volatile("s_waitcnt vmcnt(0)" ::: "memory"); }
    BARR;
    __builtin_amdgcn_sched_barrier(0);

    // ---- P5 (tile t+1, buf1): read avL + bvL ; stage B(t+2).h0 (buf0.B last read P3) ----
#pragma unroll
    for (int m_ = 0; m_ < 4; ++m_) { avL[m_][0] = RA(32768, m_, 0); avL[m_][1] = RA(32768, m_, 1); }
#pragma unroll
    for (int n_ = 0; n_ < 2; ++n_) { bvL[n_][0] = RB(32768, n_, 0); bvL[n_][1] = RB(32768, n_, 1); }
    if (more) STGB(2, 0, 0);
    BARR; LGKM0;
    MFMA8x2(avL, bvL, 0, 0);
    BARR;
    // ---- P6: read avH ; stage B(t+2).h1 ----
#pragma unroll
    for (int m_ = 0; m_ < 4; ++m_) { avH[m_][0] = RA(32768, 4 + m_, 0); avH[m_][1] = RA(32768, 4 + m_, 1); }
    if (more) STGB(2, 1, 16384);
    BARR; LGKM0;
    MFMA8x2(avH, bvL, 4, 0);
    BARR;
    // ---- P7: read bvH ; stage A(t+3).h0 -> buf1.A.h0 (buf1.A last read P6) ----
#pragma unroll
    for (int n_ = 0; n_ < 2; ++n_) { bvH[n_][0] = RB(32768, 2 + n_, 0); bvH[n_][1] = RB(32768, 2 + n_, 1); }
    if (more) STGA(3, 0, 32768);
    BARR; LGKM0;
    MFMA8x2(avH, bvH, 4, 2);
    BARR;
    // ---- P8: no reads ; stage A(t+3).h1 + B(t+3).h0 (buf1.B last read P7) ; counted wait ----
    if (more) { STGA(3, 1, 32768 + 16384); STGB(3, 0, 32768); }
    BARR;
    MFMA8x2(avL, bvH, 0, 2);
    if (more) { asm volatile("s_waitcnt vmcnt(6)" ::: "memory"); }
    BARR;
    __builtin_amdgcn_sched_barrier(0);

    pA += 128; pB += 128;
  }
#undef RA
#undef RB
#undef STGA
#undef STGB
#undef BARR
#undef LGKM0
#undef MFMA8x2

  // epilogue
#pragma unroll
  for (int m = 0; m < 8; ++m) {
    const int rb = m0 + wm * 128 + m * 16 + lg * 4;
#pragma unroll
    for (int n = 0; n < 4; ++n) {
      const int col = n0 + wn * 64 + n * 16 + lr;
      const float bv = bias[col];
#pragma unroll
      for (int r = 0; r < 4; ++r) {
        const size_t idx = (size_t)(rb + r) * N + col;
        float v = acc[m][n][r] + bv;
        if (MODE == 2) v = gelu_f(v);
        if (MODE == 3) {
          ((float*)Cout)[idx] = v + bf2f(addb[idx]) + addf[idx];
        } else {
          ((unsigned short*)Cout)[idx] = f2bf(v);
        }
      }
    }
  }
}

extern "C" void kernel_launch(void* const* d_in, const int* in_sizes, int n_in,
                              void* d_out, int out_size, void* d_ws, size_t ws_size,
                              hipStream_t stream) {
  (void)in_sizes; (void)n_in; (void)out_size; (void)ws_size;
  const float* hidden = (const float*)d_in[1];
  const float* ln_g = (const float*)d_in[2];
  const float* ln_b = (const float*)d_in[3];
  const float* wqkv = (const float*)d_in[4];
  const float* bqkv = (const float*)d_in[5];
  const float* wout = (const float*)d_in[6];
  const float* bout = (const float*)d_in[7];
  const float* wfc1 = (const float*)d_in[8];
  const float* bfc1 = (const float*)d_in[9];
  const float* wfc2 = (const float*)d_in[10];
  const float* bfc2 = (const float*)d_in[11];
  float* out = (float*)d_out;

  char* ws = (char*)d_ws;
  size_t off = 0;
  auto alloc = [&](size_t bytes) -> void* {
    void* p = ws + off;
    off += (bytes + 255) & ~(size_t)255;
    return p;
  };
  unsigned short* wqkvT = (unsigned short*)alloc((size_t)3 * DD * DD * 2);
  unsigned short* woutT = (unsigned short*)alloc((size_t)DD * DD * 2);
  unsigned short* wfc1T = (unsigned short*)alloc((size_t)NII * DD * 2);
  unsigned short* wfc2T = (unsigned short*)alloc((size_t)DD * NII * 2);
  unsigned short* xln   = (unsigned short*)alloc((size_t)NTOK * DD * 2);
  unsigned short* regA  = (unsigned short*)alloc((size_t)NTOK * NII * 2);  // qkv, then h1
  unsigned short* Qp    = (unsigned short*)alloc((size_t)2 * HH * SS * DPAD * 2);  // then attn_proj
  unsigned short* Kp    = (unsigned short*)alloc((size_t)2 * HH * SS * DPAD * 2);
  unsigned short* Vt    = (unsigned short*)alloc((size_t)2 * HH * DHH * SS * 2);
  unsigned short* Obuf  = (unsigned short*)alloc((size_t)NTOK * DD * 2);
  unsigned short* qkvbuf   = regA;
  unsigned short* h1       = regA;
  unsigned short* attnproj = Qp;

  wt_transpose<<<dim3(3 * DD / 32, DD / 32), 256, 0, stream>>>(wqkv, wqkvT, DD, 3 * DD);
  wt_transpose<<<dim3(DD / 32, DD / 32), 256, 0, stream>>>(wout, woutT, DD, DD);
  wt_transpose<<<dim3(NII / 32, DD / 32), 256, 0, stream>>>(wfc1, wfc1T, DD, NII);
  wt_transpose<<<dim3(DD / 32, NII / 32), 256, 0, stream>>>(wfc2, wfc2T, NII, DD);
  ln_kernel<<<NTOK, 256, 0, stream>>>(hidden, ln_g, ln_b, xln);
  gemm256<0><<<dim3((3 * DD / 256) * (NTOK / 256)), 512, 0, stream>>>(
      xln, wqkvT, bqkv, qkvbuf, nullptr, nullptr, NTOK, 3 * DD, DD, 3 * DD / 256);
  rope_kernel<<<NTOK, 256, 0, stream>>>(qkvbuf, Qp, Kp, Vt);
  attn_kernel<<<dim3(4096), 128, 0, stream>>>(Qp, Kp, Vt, Obuf);
  gemm256<0><<<dim3((DD / 256) * (NTOK / 256)), 512, 0, stream>>>(
      Obuf, woutT, bout, attnproj, nullptr, nullptr, NTOK, DD, DD, DD / 256);
  gemm256<2><<<dim3((NII / 256) * (NTOK / 256)), 512, 0, stream>>>(
      xln, wfc1T, bfc1, h1, nullptr, nullptr, NTOK, NII, DD, NII / 256);
  gemm256<3><<<dim3((DD / 256) * (NTOK / 256)), 512, 0, stream>>>(
      h1, wfc2T, bfc2, out, attnproj, hidden, NTOK, DD, NII, DD / 256);
}

// Round 9
// 1302.209 us; speedup vs baseline: 1.0321x; 1.0047x over previous
//
#include <hip/hip_runtime.h>

#define SS   2048
#define DD   2560
#define HH   32
#define DHH  80
#define DPAD 96
#define NII  10240
#define NTOK 4096

typedef __attribute__((ext_vector_type(8))) __bf16 bf16x8;
typedef __attribute__((ext_vector_type(4))) float  f32x4;

__device__ __forceinline__ float bf2f(unsigned short h) {
  union { unsigned u; float f; } c; c.u = ((unsigned)h) << 16; return c.f;
}
__device__ __forceinline__ unsigned short f2bf(float f) {
  union { float f; unsigned u; } c; c.f = f;
  unsigned r = c.u + 0x7FFFu + ((c.u >> 16) & 1u);
  return (unsigned short)(r >> 16);
}

__device__ __forceinline__ void gl_lds16(const void* gptr, void* lptr) {
  __builtin_amdgcn_global_load_lds((__attribute__((address_space(1))) void*)gptr,
                                   (__attribute__((address_space(3))) void*)lptr,
                                   16, 0, 0);
}

// ---------------- weight transpose: W[K][N] fp32 -> Wt[N][K] bf16 ----------------
__global__ __launch_bounds__(256) void wt_transpose(const float* __restrict__ W,
                                                    unsigned short* __restrict__ Wt,
                                                    int K, int N) {
  __shared__ float tile[32][33];
  const int tx = threadIdx.x & 31, ty = threadIdx.x >> 5;
  const int n0 = blockIdx.x * 32, k0 = blockIdx.y * 32;
#pragma unroll
  for (int i = 0; i < 32; i += 8)
    tile[ty + i][tx] = W[(size_t)(k0 + ty + i) * N + n0 + tx];
  __syncthreads();
#pragma unroll
  for (int i = 0; i < 32; i += 8)
    Wt[(size_t)(n0 + ty + i) * K + k0 + tx] = f2bf(tile[tx][ty + i]);
}

// ---------------- LayerNorm: fp32 in -> bf16 out ----------------
__global__ __launch_bounds__(256) void ln_kernel(const float* __restrict__ X,
                                                 const float* __restrict__ G,
                                                 const float* __restrict__ Bb,
                                                 unsigned short* __restrict__ Xo) {
  const int row = blockIdx.x;
  const float4* xr = (const float4*)(X + (size_t)row * DD);
  float s = 0.f, ss = 0.f;
  for (int i = threadIdx.x; i < DD / 4; i += 256) {
    float4 v = xr[i];
    s  += v.x + v.y + v.z + v.w;
    ss += v.x * v.x + v.y * v.y + v.z * v.z + v.w * v.w;
  }
#pragma unroll
  for (int o = 32; o > 0; o >>= 1) { s += __shfl_down(s, o, 64); ss += __shfl_down(ss, o, 64); }
  __shared__ float red[8];
  const int w = threadIdx.x >> 6;
  if ((threadIdx.x & 63) == 0) { red[w] = s; red[4 + w] = ss; }
  __syncthreads();
  if (threadIdx.x == 0) {
    float ts  = red[0] + red[1] + red[2] + red[3];
    float tss = red[4] + red[5] + red[6] + red[7];
    float mu  = ts * (1.f / DD);
    float var = tss * (1.f / DD) - mu * mu;
    red[0] = mu; red[1] = rsqrtf(var + 1e-5f);
  }
  __syncthreads();
  const float mu = red[0], rstd = red[1];
  const float4* gr = (const float4*)G;
  const float4* br = (const float4*)Bb;
  for (int i = threadIdx.x; i < DD / 4; i += 256) {
    float4 v = xr[i], g = gr[i], b = br[i];
    ushort4 o;
    o.x = f2bf((v.x - mu) * rstd * g.x + b.x);
    o.y = f2bf((v.y - mu) * rstd * g.y + b.y);
    o.z = f2bf((v.z - mu) * rstd * g.z + b.z);
    o.w = f2bf((v.w - mu) * rstd * g.w + b.w);
    *(ushort4*)&Xo[(size_t)row * DD + i * 4] = o;
  }
}

// ---------------- RoPE + head-layout ----------------
__global__ __launch_bounds__(256) void rope_kernel(const unsigned short* __restrict__ qkv,
                                                   unsigned short* __restrict__ Qp,
                                                   unsigned short* __restrict__ Kp,
                                                   unsigned short* __restrict__ Vt) {
  const int tok = blockIdx.x;
  const int b = tok / SS, s = tok % SS;
  __shared__ float cs[16], sn[16];
  if (threadIdx.x < 16) {
    float inv = powf(10000.f, -(float)threadIdx.x / 16.f);
    float ang = (float)s * inv;
    cs[threadIdx.x] = cosf(ang);
    sn[threadIdx.x] = sinf(ang);
  }
  __syncthreads();
  const unsigned short* row = qkv + (size_t)tok * (3 * DD);
  for (int idx = threadIdx.x; idx < 2 * HH * DPAD; idx += 256) {
    const int which = idx / (HH * DPAD);
    const int rrem  = idx % (HH * DPAD);
    const int h = rrem / DPAD, d = rrem % DPAD;
    float val = 0.f;
    if (d < DHH) {
      const unsigned short* base = row + which * DD + h * DHH;
      if (d < 16) {
        float x1 = bf2f(base[d]), x2 = bf2f(base[d + 16]);
        val = x1 * cs[d] - x2 * sn[d];
      } else if (d < 32) {
        int i2 = d - 16;
        float x1 = bf2f(base[i2]), x2 = bf2f(base[d]);
        val = x2 * cs[i2] + x1 * sn[i2];
      } else {
        val = bf2f(base[d]);
      }
    }
    unsigned short* outp = which ? Kp : Qp;
    outp[(((size_t)b * HH + h) * SS + s) * DPAD + d] = f2bf(val);
  }
  for (int idx = threadIdx.x; idx < DD; idx += 256) {
    const int h = idx / DHH, d = idx % DHH;
    Vt[(((size_t)b * HH + h) * DHH + d) * SS + s] = row[2 * DD + idx];
  }
}

// ---------------- flash attention (causal), 2-wave blocks, 16 q-rows/wave, KVBLK=64 ----------------
__global__ __launch_bounds__(128) void attn_kernel(const unsigned short* __restrict__ Qp,
                                                   const unsigned short* __restrict__ Kp,
                                                   const unsigned short* __restrict__ Vt,
                                                   unsigned short* __restrict__ O) {
  const int bid = blockIdx.x;
  const int bh = bid & 63;
  const int p = 63 - (bid >> 6);        // heavy first
  const int w = threadIdx.x >> 6;
  const int tile = p * 2 + w;
  const int lane = threadIdx.x & 63;
  const int lr = lane & 15, lg = lane >> 4;
  const int q0 = tile * 16;
  const unsigned short* Qh = Qp + (size_t)bh * SS * DPAD;
  const unsigned short* Kh = Kp + (size_t)bh * SS * DPAD;
  const unsigned short* Vh = Vt + (size_t)bh * DHH * SS;
  __shared__ __align__(16) char Plds[2][2048];
  char* Pb = Plds[w];

  bf16x8 qf[3];
#pragma unroll
  for (int c = 0; c < 3; ++c)
    qf[c] = *(const bf16x8*)&Qh[(size_t)(q0 + lr) * DPAD + c * 32 + lg * 8];

  f32x4 oacc[5];
#pragma unroll
  for (int d = 0; d < 5; ++d) oacc[d] = (f32x4){0.f, 0.f, 0.f, 0.f};
  float mrow[4], lrow[4];
#pragma unroll
  for (int r = 0; r < 4; ++r) { mrow[r] = -1e30f; lrow[r] = 0.f; }

  const float scl = 0.11180339887498949f;
  const int nt = q0 / 64 + 1;
  for (int t = 0; t < nt; ++t) {
    const int kv0 = t * 64;
    f32x4 s0 = (f32x4){0.f, 0.f, 0.f, 0.f};
    f32x4 s1 = (f32x4){0.f, 0.f, 0.f, 0.f};
    f32x4 s2 = (f32x4){0.f, 0.f, 0.f, 0.f};
    f32x4 s3 = (f32x4){0.f, 0.f, 0.f, 0.f};
#pragma unroll
    for (int c = 0; c < 3; ++c) {
      bf16x8 k0 = *(const bf16x8*)&Kh[(size_t)(kv0 +      lr) * DPAD + c * 32 + lg * 8];
      bf16x8 k1 = *(const bf16x8*)&Kh[(size_t)(kv0 + 16 + lr) * DPAD + c * 32 + lg * 8];
      bf16x8 k2 = *(const bf16x8*)&Kh[(size_t)(kv0 + 32 + lr) * DPAD + c * 32 + lg * 8];
      bf16x8 k3 = *(const bf16x8*)&Kh[(size_t)(kv0 + 48 + lr) * DPAD + c * 32 + lg * 8];
      s0 = __builtin_amdgcn_mfma_f32_16x16x32_bf16(qf[c], k0, s0, 0, 0, 0);
      s1 = __builtin_amdgcn_mfma_f32_16x16x32_bf16(qf[c], k1, s1, 0, 0, 0);
      s2 = __builtin_amdgcn_mfma_f32_16x16x32_bf16(qf[c], k2, s2, 0, 0, 0);
      s3 = __builtin_amdgcn_mfma_f32_16x16x32_bf16(qf[c], k3, s3, 0, 0, 0);
    }
    float pv0[4], pv1[4], pv2[4], pv3[4], mx[4];
    bool need = false;
#pragma unroll
    for (int r = 0; r < 4; ++r) {
      const int qr = q0 + lg * 4 + r;
      float a0 = (kv0 +      lr > qr) ? -1e30f : s0[r] * scl;
      float a1 = (kv0 + 16 + lr > qr) ? -1e30f : s1[r] * scl;
      float a2 = (kv0 + 32 + lr > qr) ? -1e30f : s2[r] * scl;
      float a3 = (kv0 + 48 + lr > qr) ? -1e30f : s3[r] * scl;
      pv0[r] = a0; pv1[r] = a1; pv2[r] = a2; pv3[r] = a3;
      float m = fmaxf(fmaxf(a0, a1), fmaxf(a2, a3));
#pragma unroll
      for (int mk = 1; mk < 16; mk <<= 1) m = fmaxf(m, __shfl_xor(m, mk, 64));
      mx[r] = m;
      need = need || (m > mrow[r] + 8.f);
    }
    if (__ballot(need)) {
#pragma unroll
      for (int r = 0; r < 4; ++r) {
        float mnew = fmaxf(mrow[r], mx[r]);
        float resc = __expf(mrow[r] - mnew);
        lrow[r] *= resc;
#pragma unroll
        for (int d = 0; d < 5; ++d) oacc[d][r] *= resc;
        mrow[r] = mnew;
      }
    }
#pragma unroll
    for (int r = 0; r < 4; ++r) {
      const int row = lg * 4 + r;
      const int swz = (row & 7) << 4;
      float p0 = __expf(pv0[r] - mrow[r]);
      float p1 = __expf(pv1[r] - mrow[r]);
      float p2 = __expf(pv2[r] - mrow[r]);
      float p3 = __expf(pv3[r] - mrow[r]);
      *(unsigned short*)(Pb + row * 128 + ((( 0 + lr) * 2) ^ swz)) = f2bf(p0);
      *(unsigned short*)(Pb + row * 128 + (((16 + lr) * 2) ^ swz)) = f2bf(p1);
      *(unsigned short*)(Pb + row * 128 + (((32 + lr) * 2) ^ swz)) = f2bf(p2);
      *(unsigned short*)(Pb + row * 128 + (((48 + lr) * 2) ^ swz)) = f2bf(p3);
      float rs = (p0 + p1) + (p2 + p3);
#pragma unroll
      for (int mk = 1; mk < 16; mk <<= 1) rs += __shfl_xor(rs, mk, 64);
      lrow[r] += rs;
    }
    asm volatile("s_waitcnt lgkmcnt(0)" ::: "memory");
    const int rswz = (lr & 7) << 4;
    bf16x8 pa0 = *(const bf16x8*)(Pb + lr * 128 + ((lg * 16) ^ rswz));
    bf16x8 pa1 = *(const bf16x8*)(Pb + lr * 128 + ((64 + lg * 16) ^ rswz));
#pragma unroll
    for (int d = 0; d < 5; ++d) {
      bf16x8 v0 = *(const bf16x8*)&Vh[(size_t)(d * 16 + lr) * SS + kv0 + lg * 8];
      bf16x8 v1 = *(const bf16x8*)&Vh[(size_t)(d * 16 + lr) * SS + kv0 + 32 + lg * 8];
      oacc[d] = __builtin_amdgcn_mfma_f32_16x16x32_bf16(pa0, v0, oacc[d], 0, 0, 0);
      oacc[d] = __builtin_amdgcn_mfma_f32_16x16x32_bf16(pa1, v1, oacc[d], 0, 0, 0);
    }
  }
  const int b = bh >> 5, h = bh & 31;
#pragma unroll
  for (int r = 0; r < 4; ++r) {
    const int qr = q0 + lg * 4 + r;
    const float inv = 1.f / lrow[r];
#pragma unroll
    for (int d = 0; d < 5; ++d)
      O[(size_t)(b * SS + qr) * DD + h * DHH + d * 16 + lr] = f2bf(oacc[d][r] * inv);
  }
}

// ---------------- 256x256 GEMM, 8 waves (2Mx4N), BK=64, 8-phase counted-vmcnt ----------------
__device__ __forceinline__ float gelu_f(float x) {
  float x3 = x * x * x;
  return 0.5f * x * (1.f + tanhf(0.7978845608028654f * (x + 0.044715f * x3)));
}

// LDS 128 KB: A [buf][Mhalf][128 rows][64 k] bf16 at buf*32768 + half*16384; B same at +65536.
// Block mapping: by = bid % nby, bx = bid / nby (column-major). With round-robin XCD dispatch
// each XCD's resident blocks form a 2-by x 16-bx rectangle -> A panels L2-resident, reused 16x.
// Race-free ledger (r8, verified): read windows buf0.A:{P1,P2} buf0.B:{P1,P3} buf1.A:{P5,P6} buf1.B:{P5,P7};
// stages P1:B(t+1)h1 P3:A(t+2)h0 P4:A(t+2)h1 P5:B(t+2)h0 P6:B(t+2)h1 P7:A(t+3)h0 P8:A(t+3)h1+B(t+3)h0;
// vmcnt(4) at P4-end completes tile t+1; vmcnt(6) at P8-end completes tile t+2; entry invariant 6.
template <int MODE>
__global__ __launch_bounds__(512, 2) void gemm256(const unsigned short* __restrict__ A,
                                                  const unsigned short* __restrict__ Bt,
                                                  const float* __restrict__ bias,
                                                  void* __restrict__ Cout,
                                                  const unsigned short* __restrict__ addb,
                                                  const float* __restrict__ addf,
                                                  int M, int N, int K, int nby) {
  __shared__ __align__(16) char lds[131072];

  const int bid = blockIdx.x;
  const int by = bid % nby, bx = bid / nby;
  const int m0 = by * 256, n0 = bx * 256;

  const int tid = threadIdx.x;
  const int w = tid >> 6, lane = tid & 63;
  const int lr = lane & 15, lg = lane >> 4;
  const int wm = w >> 2, wn = w & 3;   // 2M x 4N; wave tile 128x64

  // staging: half-tile (128 rows x 64k), 16 rows/wave, 2 gl_lds; pre-swizzled source k-slot.
  const int srow = w * 16 + (lane >> 3);
  const int scol = ((lane & 7) ^ ((lane >> 3) & 7)) * 8;
  const unsigned short* pA = A  + (size_t)(m0 + srow) * K + scol;
  const unsigned short* pB = Bt + (size_t)(n0 + srow) * K + scol;
  const int wdst = w * 2048;

  // fragment reads: half = wm (A) / wn>>1 (B); row*128B; swizzled 16B slot.
  const int rdA = wm * 16384 + lr * 128;
  const int rdB = 65536 + (wn >> 1) * 16384 + ((wn & 1) * 64 + lr) * 128;
  const int sl0 = ((lg) ^ (lr & 7)) << 4;
  const int sl1 = ((4 + lg) ^ (lr & 7)) << 4;

  f32x4 acc[8][4];
#pragma unroll
  for (int i = 0; i < 8; ++i)
#pragma unroll
    for (int j = 0; j < 4; ++j) acc[i][j] = (f32x4){0.f, 0.f, 0.f, 0.f};

  const int nt = K >> 6;  // K-tiles of 64; even for all shapes here (40 / 160)

#define RA(BUF, m, kh) (*(const bf16x8*)(lds + (BUF) + rdA + (m) * 2048 + ((kh) ? sl1 : sl0)))
#define RB(BUF, n, kh) (*(const bf16x8*)(lds + (BUF) + rdB + (n) * 2048 + ((kh) ? sl1 : sl0)))
#define STGA(dt, h, DST)                                                       \
  { const unsigned short* s_ = pA + (size_t)(dt) * 64 + (size_t)(h) * 128 * K; \
    gl_lds16(s_,                 lds + (DST) + wdst);                          \
    gl_lds16(s_ + (size_t)8 * K, lds + (DST) + wdst + 1024); }
#define STGB(dt, h, DST)                                                       \
  { const unsigned short* s_ = pB + (size_t)(dt) * 64 + (size_t)(h) * 128 * K; \
    gl_lds16(s_,                 lds + 65536 + (DST) + wdst);                  \
    gl_lds16(s_ + (size_t)8 * K, lds + 65536 + (DST) + wdst + 1024); }
#define BARR __builtin_amdgcn_s_barrier()
#define MFMA8x2(AV, BV, MB, NB)                                              \
  __builtin_amdgcn_s_setprio(1);                                             \
  _Pragma("unroll") for (int kh_ = 0; kh_ < 2; ++kh_)                        \
  _Pragma("unroll") for (int m_ = 0; m_ < 4; ++m_)                           \
  _Pragma("unroll") for (int n_ = 0; n_ < 2; ++n_)                           \
    acc[(MB) + m_][(NB) + n_] = __builtin_amdgcn_mfma_f32_16x16x32_bf16(     \
        AV[m_][kh_], BV[n_][kh_], acc[(MB) + m_][(NB) + n_], 0, 0, 0);       \
  __builtin_amdgcn_s_setprio(0);

  // ---- prologue: tile0 (4 HT) fully; tile1 {A.h0, A.h1, B.h0} left in flight (6 loads) ----
  STGA(0, 0, 0);
  STGA(0, 1, 16384);
  STGB(0, 0, 0);
  STGB(0, 1, 16384);
  STGA(1, 0, 32768);
  STGA(1, 1, 32768 + 16384);
  STGB(1, 0, 32768);
  asm volatile("s_waitcnt vmcnt(6)" ::: "memory");
  BARR;
  __builtin_amdgcn_sched_barrier(0);

  for (int t = 0; t < nt; t += 2) {
    const bool more = (t + 2 < nt);  // false only on the final iteration (nt even)
    bf16x8 avL[4][2], avH[4][2], bvL[2][2], bvH[2][2];

    // ---- P1 (tile t, buf0): read avL + bvL ; stage B(t+1).h1 -> buf1.B.h1 ----
#pragma unroll
    for (int m_ = 0; m_ < 4; ++m_) { avL[m_][0] = RA(0, m_, 0); avL[m_][1] = RA(0, m_, 1); }
#pragma unroll
    for (int n_ = 0; n_ < 2; ++n_) { bvL[n_][0] = RB(0, n_, 0); bvL[n_][1] = RB(0, n_, 1); }
    STGB(1, 1, 32768 + 16384);
    BARR;
    MFMA8x2(avL, bvL, 0, 0);
    BARR;
    // ---- P2: read avH ----
#pragma unroll
    for (int m_ = 0; m_ < 4; ++m_) { avH[m_][0] = RA(0, 4 + m_, 0); avH[m_][1] = RA(0, 4 + m_, 1); }
    BARR;
    MFMA8x2(avH, bvL, 4, 0);
    BARR;
    // ---- P3: read bvH ; stage A(t+2).h0 (buf0.A last read P2) ----
#pragma unroll
    for (int n_ = 0; n_ < 2; ++n_) { bvH[n_][0] = RB(0, 2 + n_, 0); bvH[n_][1] = RB(0, 2 + n_, 1); }
    if (more) STGA(2, 0, 0);
    BARR;
    MFMA8x2(avH, bvH, 4, 2);
    BARR;
    // ---- P4: no reads ; stage A(t+2).h1 ; counted wait ----
    if (more) STGA(2, 1, 16384);
    BARR;
    MFMA8x2(avL, bvH, 0, 2);
    if (more) { asm volatile("s_waitcnt vmcnt(4)" ::: "memory"); }
    else      { asm volatile("s_waitcnt vmcnt(0)" ::: "memory"); }
    BARR;
    __builtin_amdgcn_sched_barrier(0);

    // ---- P5 (tile t+1, buf1): read avL + bvL ; stage B(t+2).h0 (buf0.B last read P3) ----
#pragma unroll
    for (int m_ = 0; m_ < 4; ++m_) { avL[m_][0] = RA(32768, m_, 0); avL[m_][1] = RA(32768, m_, 1); }
#pragma unroll
    for (int n_ = 0; n_ < 2; ++n_) { bvL[n_][0] = RB(32768, n_, 0); bvL[n_][1] = RB(32768, n_, 1); }
    if (more) STGB(2, 0, 0);
    BARR;
    MFMA8x2(avL, bvL, 0, 0);
    BARR;
    // ---- P6: read avH ; stage B(t+2).h1 ----
#pragma unroll
    for (int m_ = 0; m_ < 4; ++m_) { avH[m_][0] = RA(32768, 4 + m_, 0); avH[m_][1] = RA(32768, 4 + m_, 1); }
    if (more) STGB(2, 1, 16384);
    BARR;
    MFMA8x2(avH, bvL, 4, 0);
    BARR;
    // ---- P7: read bvH ; stage A(t+3).h0 (buf1.A last read P6) ----
#pragma unroll
    for (int n_ = 0; n_ < 2; ++n_) { bvH[n_][0] = RB(32768, 2 + n_, 0); bvH[n_][1] = RB(32768, 2 + n_, 1); }
    if (more) STGA(3, 0, 32768);
    BARR;
    MFMA8x2(avH, bvH, 4, 2);
    BARR;
    // ---- P8: no reads ; stage A(t+3).h1 + B(t+3).h0 (buf1.B last read P7) ; counted wait ----
    if (more) { STGA(3, 1, 32768 + 16384); STGB(3, 0, 32768); }
    BARR;
    MFMA8x2(avL, bvH, 0, 2);
    if (more) { asm volatile("s_waitcnt vmcnt(6)" ::: "memory"); }
    BARR;
    __builtin_amdgcn_sched_barrier(0);

    pA += 128; pB += 128;
  }
#undef RA
#undef RB
#undef STGA
#undef STGB
#undef BARR
#undef MFMA8x2

  // epilogue
#pragma unroll
  for (int m = 0; m < 8; ++m) {
    const int rb = m0 + wm * 128 + m * 16 + lg * 4;
#pragma unroll
    for (int n = 0; n < 4; ++n) {
      const int col = n0 + wn * 64 + n * 16 + lr;
      const float bv = bias[col];
#pragma unroll
      for (int r = 0; r < 4; ++r) {
        const size_t idx = (size_t)(rb + r) * N + col;
        float v = acc[m][n][r] + bv;
        if (MODE == 2) v = gelu_f(v);
        if (MODE == 3) {
          ((float*)Cout)[idx] = v + bf2f(addb[idx]) + addf[idx];
        } else {
          ((unsigned short*)Cout)[idx] = f2bf(v);
        }
      }
    }
  }
}

extern "C" void kernel_launch(void* const* d_in, const int* in_sizes, int n_in,
                              void* d_out, int out_size, void* d_ws, size_t ws_size,
                              hipStream_t stream) {
  (void)in_sizes; (void)n_in; (void)out_size; (void)ws_size;
  const float* hidden = (const float*)d_in[1];
  const float* ln_g = (const float*)d_in[2];
  const float* ln_b = (const float*)d_in[3];
  const float* wqkv = (const float*)d_in[4];
  const float* bqkv = (const float*)d_in[5];
  const float* wout = (const float*)d_in[6];
  const float* bout = (const float*)d_in[7];
  const float* wfc1 = (const float*)d_in[8];
  const float* bfc1 = (const float*)d_in[9];
  const float* wfc2 = (const float*)d_in[10];
  const float* bfc2 = (const float*)d_in[11];
  float* out = (float*)d_out;

  char* ws = (char*)d_ws;
  size_t off = 0;
  auto alloc = [&](size_t bytes) -> void* {
    void* p = ws + off;
    off += (bytes + 255) & ~(size_t)255;
    return p;
  };
  unsigned short* wqkvT = (unsigned short*)alloc((size_t)3 * DD * DD * 2);
  unsigned short* woutT = (unsigned short*)alloc((size_t)DD * DD * 2);
  unsigned short* wfc1T = (unsigned short*)alloc((size_t)NII * DD * 2);
  unsigned short* wfc2T = (unsigned short*)alloc((size_t)DD * NII * 2);
  unsigned short* xln   = (unsigned short*)alloc((size_t)NTOK * DD * 2);
  unsigned short* regA  = (unsigned short*)alloc((size_t)NTOK * NII * 2);  // qkv, then h1
  unsigned short* Qp    = (unsigned short*)alloc((size_t)2 * HH * SS * DPAD * 2);  // then attn_proj
  unsigned short* Kp    = (unsigned short*)alloc((size_t)2 * HH * SS * DPAD * 2);
  unsigned short* Vt    = (unsigned short*)alloc((size_t)2 * HH * DHH * SS * 2);
  unsigned short* Obuf  = (unsigned short*)alloc((size_t)NTOK * DD * 2);
  unsigned short* qkvbuf   = regA;
  unsigned short* h1       = regA;
  unsigned short* attnproj = Qp;

  wt_transpose<<<dim3(3 * DD / 32, DD / 32), 256, 0, stream>>>(wqkv, wqkvT, DD, 3 * DD);
  wt_transpose<<<dim3(DD / 32, DD / 32), 256, 0, stream>>>(wout, woutT, DD, DD);
  wt_transpose<<<dim3(NII / 32, DD / 32), 256, 0, stream>>>(wfc1, wfc1T, DD, NII);
  wt_transpose<<<dim3(DD / 32, NII / 32), 256, 0, stream>>>(wfc2, wfc2T, NII, DD);
  ln_kernel<<<NTOK, 256, 0, stream>>>(hidden, ln_g, ln_b, xln);
  gemm256<0><<<dim3((3 * DD / 256) * (NTOK / 256)), 512, 0, stream>>>(
      xln, wqkvT, bqkv, qkvbuf, nullptr, nullptr, NTOK, 3 * DD, DD, NTOK / 256);
  rope_kernel<<<NTOK, 256, 0, stream>>>(qkvbuf, Qp, Kp, Vt);
  attn_kernel<<<dim3(4096), 128, 0, stream>>>(Qp, Kp, Vt, Obuf);
  gemm256<0><<<dim3((DD / 256) * (NTOK / 256)), 512, 0, stream>>>(
      Obuf, woutT, bout, attnproj, nullptr, nullptr, NTOK, DD, DD, NTOK / 256);
  gemm256<2><<<dim3((NII / 256) * (NTOK / 256)), 512, 0, stream>>>(
      xln, wfc1T, bfc1, h1, nullptr, nullptr, NTOK, NII, DD, NTOK / 256);
  gemm256<3><<<dim3((DD / 256) * (NTOK / 256)), 512, 0, stream>>>(
      h1, wfc2T, bfc2, out, attnproj, hidden, NTOK, DD, NII, NTOK / 256);
}